// Round 2
// baseline (4117.965 us; speedup 1.0000x reference)
//
#include <hip/hip_runtime.h>
#include <hip/hip_bf16.h>
#include <math.h>

#define NN_ 2048

__device__ __forceinline__ float geluf(float x){ return 0.5f*x*(1.0f+erff(x*0.70710678118654752440f)); }
__device__ __forceinline__ float gelupf(float x){
  float cdf = 0.5f*(1.0f+erff(x*0.70710678118654752440f));
  float pdf = 0.39894228040143267794f*expf(-0.5f*x*x);
  return cdf + x*pdf;
}
__device__ __forceinline__ float sigm(float x){ return 1.0f/(1.0f+expf(-x)); }

// ---------------- rmsnorm of seq with store/retrieve gains ----------------
__global__ __launch_bounds__(256) void k_rmsnorm(const float* __restrict__ seq, const float* __restrict__ gs,
                          const float* __restrict__ gr, float* __restrict__ S, float* __restrict__ SR){
  int tok = blockIdx.x;
  const float* row = seq + (size_t)tok*512;
  int tid = threadIdx.x;
  float x0 = row[tid];
  float x1 = row[tid+256];
  float ss = x0*x0 + x1*x1;
  #pragma unroll
  for (int o=32;o>0;o>>=1) ss += __shfl_down(ss, o, 64);
  __shared__ float wsum[4];
  int wid = tid>>6, lid = tid&63;
  if (lid==0) wsum[wid]=ss;
  __syncthreads();
  float tot = wsum[0]+wsum[1]+wsum[2]+wsum[3];
  float r = rsqrtf(tot*(1.0f/512.0f) + 1e-6f);
  size_t o0 = (size_t)tok*512 + tid;
  S[o0]      = x0*r*gs[tid];
  S[o0+256]  = x1*r*gs[tid+256];
  SR[o0]     = x0*r*gr[tid];
  SR[o0+256] = x1*r*gr[tid+256];
}

// ---------------- generic tiled GEMM: (4096x512 f32) @ (512x512 f32) ----------------
__global__ __launch_bounds__(256) void k_gemm(const float* __restrict__ X, const float* __restrict__ Wt,
                       float* __restrict__ O){
  __shared__ float Xs[64][33];
  __shared__ float Ws[32][65];
  int rt = blockIdx.x, ct = blockIdx.y, tid = threadIdx.x;
  int r0 = (tid>>4)*4, c0 = (tid&15)*4;
  float acc[4][4] = {};
  for (int k0=0;k0<512;k0+=32){
    for (int idx=tid; idx<2048; idx+=256){
      int r = idx>>5, kk = idx&31;
      Xs[r][kk] = X[(size_t)(rt*64+r)*512 + (k0+kk)];
    }
    for (int idx=tid; idx<2048; idx+=256){
      int kk = idx>>6, c = idx&63;
      Ws[kk][c] = Wt[(size_t)(k0+kk)*512 + (ct*64+c)];
    }
    __syncthreads();
    #pragma unroll 8
    for (int kk=0;kk<32;kk++){
      float xv[4], wv[4];
      #pragma unroll
      for (int i=0;i<4;i++) xv[i]=Xs[r0+i][kk];
      #pragma unroll
      for (int j=0;j<4;j++) wv[j]=Ws[kk][c0+j];
      #pragma unroll
      for (int i=0;i<4;i++)
        #pragma unroll
        for (int j=0;j<4;j++) acc[i][j] += xv[i]*wv[j];
    }
    __syncthreads();
  }
  for (int i=0;i<4;i++)
    for (int j=0;j<4;j++){
      size_t row = (size_t)rt*64+r0+i, col = (size_t)ct*64+c0+j;
      O[row*512+col] = acc[i][j];
    }
}

// ---------------- lr/gate per token, pooled->mom/dec per chunk ----------------
__global__ __launch_bounds__(256) void k_small(const float* __restrict__ S, const float* __restrict__ SR,
    const float* __restrict__ Wlr, const float* __restrict__ blr, const float* __restrict__ Wm,
    const float* __restrict__ bm, const float* __restrict__ Wd, const float* __restrict__ bd,
    const float* __restrict__ Wgate,
    float* __restrict__ LRb, float* __restrict__ GATEb, float* __restrict__ MOMb, float* __restrict__ DECb){
  int bc = blockIdx.x;            // b*32 + ci
  int b = bc>>5, ci = bc&31;
  int tid = threadIdx.x;
  int t = tid>>2, h = tid&3;
  size_t tokbase = (size_t)b*NN_ + (size_t)ci*64;
  __shared__ float pool[512];
  for (int c=tid; c<512; c+=256){
    float s=0;
    for (int t2=0;t2<64;t2++) s += S[(tokbase+t2)*512 + c];
    pool[c] = s*(1.0f/64.0f);
  }
  size_t tok = tokbase + t;
  const float* srow = S + tok*512;
  const float* srrow = SR + tok*512;
  float accl=0, accg=0;
  for (int d=0; d<512; d++){
    accl += srow[d]*Wlr[d*4+h];
    accg += srrow[d]*Wgate[d*4+h];
  }
  accl += blr[h];
  LRb[tok*4+h] = sigm(accl);
  GATEb[tok*4+h] = sigm(accg);
  __syncthreads();
  if (tid<8){
    int hh = tid&3, which = tid>>2;
    float a=0;
    const float* Wx = which? Wd : Wm;
    for (int d=0; d<512; d++) a += pool[d]*Wx[d*4+hh];
    a += which? bd[hh] : bm[hh];
    float v = sigm(a);
    size_t o = ((size_t)b*4+hh)*32 + ci;
    if (which) DECb[o]=v; else MOMb[o]=v;
  }
}

// ---------------- fused memory-MLP forward + rmsnorm backward (per chunk) ----------------
__global__ __launch_bounds__(512) void k_fwd(const float* __restrict__ Kb, const float* __restrict__ Vb,
    const float* __restrict__ LRb, const float* __restrict__ mw1, const float* __restrict__ mw2,
    const float* __restrict__ mgamma, float* __restrict__ H1B, float* __restrict__ DH2,
    float* __restrict__ GG){
  int inst = blockIdx.x;
  int ci = inst & 31, h = (inst>>5)&3, b = inst>>7;
  size_t tok0 = (size_t)b*NN_ + (size_t)ci*64;
  int tid = threadIdx.x;
  __shared__ float xs[64][129];
  __shared__ float wbuf[4224];
  __shared__ float as_[64][33];
  __shared__ float red[64][17];
  __shared__ float sgg[128];
  __shared__ float rr[64], lrs[64], dotl[64];
  #define W1S(d,j) wbuf[(d)*33+(j)]
  #define W2S(j,d) wbuf[(j)*130+(d)]
  for (int idx=tid; idx<8192; idx+=512){
    int t = idx>>7, d = idx&127;
    xs[t][d] = Kb[(tok0+t)*512 + h*128 + d];
  }
  if (tid<64) lrs[tid] = LRb[(tok0+tid)*4 + h];
  if (tid<128) sgg[tid]=0.0f;
  __syncthreads();
  int tg = tid>>4, dq = tid&15;
  int t0 = tg*2, d0 = dq*8;
  float h2a[2][8] = {};
  for (int jt=0;jt<16;jt++){
    int j0 = jt*32;
    for (int idx=tid; idx<4096; idx+=512){
      int d = idx>>5, jj = idx&31;
      W1S(d,jj) = mw1[(size_t)h*65536 + (size_t)d*512 + (j0+jj)];
    }
    __syncthreads();
    {
      int jj0 = dq*2;
      float a00=0,a01=0,a10=0,a11=0;
      for (int d=0; d<128; d++){
        float x0=xs[t0][d], x1=xs[t0+1][d];
        float w0=W1S(d,jj0), w1v=W1S(d,jj0+1);
        a00+=x0*w0; a01+=x0*w1v; a10+=x1*w0; a11+=x1*w1v;
      }
      size_t hb = (size_t)inst*32768;
      H1B[hb + (size_t)t0*512 + j0+jj0]       = a00;
      H1B[hb + (size_t)t0*512 + j0+jj0+1]     = a01;
      H1B[hb + (size_t)(t0+1)*512 + j0+jj0]   = a10;
      H1B[hb + (size_t)(t0+1)*512 + j0+jj0+1] = a11;
      as_[t0][jj0]=geluf(a00);   as_[t0][jj0+1]=geluf(a01);
      as_[t0+1][jj0]=geluf(a10); as_[t0+1][jj0+1]=geluf(a11);
    }
    __syncthreads();
    for (int idx=tid; idx<4096; idx+=512){
      int jj = idx>>7, d = idx&127;
      W2S(jj,d) = mw2[(size_t)h*65536 + (size_t)(j0+jj)*128 + d];
    }
    __syncthreads();
    for (int jj=0;jj<32;jj++){
      float a0=as_[t0][jj], a1=as_[t0+1][jj];
      #pragma unroll
      for (int j2=0;j2<8;j2++){
        float wv = W2S(jj, d0+j2);
        h2a[0][j2]+=a0*wv; h2a[1][j2]+=a1*wv;
      }
    }
    __syncthreads();
  }
  float ss0=0, ss1=0;
  #pragma unroll
  for (int j=0;j<8;j++){ ss0+=h2a[0][j]*h2a[0][j]; ss1+=h2a[1][j]*h2a[1][j]; }
  red[t0][dq]=ss0; red[t0+1][dq]=ss1;
  __syncthreads();
  if (tid<64){
    float s=0;
    #pragma unroll
    for (int q=0;q<16;q++) s+=red[tid][q];
    rr[tid] = rsqrtf(s*(1.0f/128.0f) + 1e-6f);
  }
  __syncthreads();
  float dn[2][8]; float dot0=0, dot1=0; float ggp[8]={};
  for (int i=0;i<2;i++){
    int t=t0+i;
    float r = rr[t];
    float lrv = lrs[t]*(2.0f/128.0f);
    #pragma unroll
    for (int j=0;j<8;j++){
      int d = d0+j;
      float nval = h2a[i][j]*r;
      float gv = mgamma[h*128+d];
      float pred = nval*gv + xs[t][d];
      float dp = lrv*(pred - Vb[(tok0+t)*512 + h*128 + d]);
      ggp[j] += dp*nval;
      float dnv = dp*gv;
      dn[i][j]=dnv;
      if (i==0) dot0 += dnv*h2a[i][j]; else dot1 += dnv*h2a[i][j];
    }
  }
  #pragma unroll
  for (int j=0;j<8;j++) atomicAdd(&sgg[d0+j], ggp[j]);
  red[t0][dq]=dot0; red[t0+1][dq]=dot1;
  __syncthreads();
  if (tid<64){
    float s=0;
    #pragma unroll
    for (int q=0;q<16;q++) s+=red[tid][q];
    dotl[tid]=s;
  }
  __syncthreads();
  for (int i=0;i<2;i++){
    int t=t0+i; float r=rr[t];
    float dt = dotl[t]*r*r*r*(1.0f/128.0f);
    #pragma unroll
    for (int j=0;j<8;j++)
      DH2[(size_t)inst*8192 + (size_t)t*128 + d0+j] = r*dn[i][j] - dt*h2a[i][j];
  }
  if (tid<128) GG[(size_t)inst*128+tid] = -sgg[tid];
  #undef W1S
  #undef W2S
}

// ---------------- G2T[d][j] = -sum_t gelu(h1[t,j]) * dh2[t,d]  ----------------
__global__ __launch_bounds__(256) void k_dw2(const float* __restrict__ H1B, const float* __restrict__ DH2,
                      float* __restrict__ G2T){
  int inst = blockIdx.x>>3;
  int jt = blockIdx.x&7; int j0 = jt*64;
  int tid = threadIdx.x;
  __shared__ float dh2s[64][129];
  __shared__ float as2[64][65];
  for (int idx=tid; idx<8192; idx+=256){ int t=idx>>7, d=idx&127; dh2s[t][d]=DH2[(size_t)inst*8192+idx]; }
  for (int idx=tid; idx<4096; idx+=256){ int t=idx>>6, jj=idx&63; as2[t][jj]=geluf(H1B[(size_t)inst*32768+(size_t)t*512+j0+jj]); }
  __syncthreads();
  int dg=tid>>3, jg=tid&7; int d0=dg*4, jj0=jg*8;
  float acc[4][8]={};
  for (int t=0;t<64;t++){
    float dv[4], av[8];
    #pragma unroll
    for (int i=0;i<4;i++) dv[i]=dh2s[t][d0+i];
    #pragma unroll
    for (int j=0;j<8;j++) av[j]=as2[t][jj0+j];
    #pragma unroll
    for (int i=0;i<4;i++)
      #pragma unroll
      for (int j=0;j<8;j++) acc[i][j]+=av[j]*dv[i];
  }
  for (int i=0;i<4;i++)
    #pragma unroll
    for (int j=0;j<8;j++)
      G2T[(size_t)inst*65536 + (size_t)(d0+i)*512 + j0+jj0+j] = -acc[i][j];
}

// ---------------- da = dh2 @ w2^T ; dh1 = da*gelu'(h1); G1 = -x^T @ dh1 ----------------
__global__ __launch_bounds__(256) void k_dw1(const float* __restrict__ Kb, const float* __restrict__ DH2,
    const float* __restrict__ H1B, const float* __restrict__ mw2, float* __restrict__ G1){
  int inst = blockIdx.x>>4; int jt = blockIdx.x&15; int j0=jt*32;
  int ci = inst&31, h=(inst>>5)&3, b=inst>>7;
  size_t tok0 = (size_t)b*NN_ + (size_t)ci*64;
  int tid=threadIdx.x;
  __shared__ float buf[64][129];
  __shared__ float w2s[32][130];
  __shared__ float dh1s[64][33];
  for (int idx=tid; idx<8192; idx+=256){ int t=idx>>7, d=idx&127; buf[t][d]=DH2[(size_t)inst*8192+idx]; }
  for (int idx=tid; idx<4096; idx+=256){ int jj=idx>>7, d=idx&127; w2s[jj][d]=mw2[(size_t)h*65536+(size_t)(j0+jj)*128+d]; }
  __syncthreads();
  int tg=tid>>3, jg=tid&7; int t0=tg*2, jj0=jg*4;
  float da[2][4]={};
  for (int d=0; d<128; d++){
    float q0=buf[t0][d], q1=buf[t0+1][d];
    #pragma unroll
    for (int j=0;j<4;j++){ float wv=w2s[jj0+j][d]; da[0][j]+=q0*wv; da[1][j]+=q1*wv; }
  }
  float dh1v[2][4];
  for (int i=0;i<2;i++)
    for (int j=0;j<4;j++){
      float hv = H1B[(size_t)inst*32768 + (size_t)(t0+i)*512 + j0+jj0+j];
      dh1v[i][j] = da[i][j]*gelupf(hv);
    }
  __syncthreads();
  for (int i=0;i<2;i++)
    for (int j=0;j<4;j++) dh1s[t0+i][jj0+j]=dh1v[i][j];
  for (int idx=tid; idx<8192; idx+=256){ int t=idx>>7, d=idx&127; buf[t][d]=Kb[(tok0+t)*512 + h*128 + d]; }
  __syncthreads();
  int dg=tid>>3; int d0=dg*4;
  float acc[4][4]={};
  for (int t=0;t<64;t++){
    float xv[4], hv[4];
    #pragma unroll
    for (int i=0;i<4;i++) xv[i]=buf[t][d0+i];
    #pragma unroll
    for (int j=0;j<4;j++) hv[j]=dh1s[t][jj0+j];
    #pragma unroll
    for (int i=0;i<4;i++)
      #pragma unroll
      for (int j=0;j<4;j++) acc[i][j]+=xv[i]*hv[j];
  }
  for (int i=0;i<4;i++)
    for (int j=0;j<4;j++)
      G1[(size_t)inst*65536 + (size_t)(d0+i)*512 + j0+jj0+j] = -acc[i][j];
}

// ---------------- Newton-Schulz ----------------
__global__ __launch_bounds__(512) void k_ns_prep(float* __restrict__ G1, float* __restrict__ G2T){
  int m = blockIdx.x;
  float* t = (m<256)? (G1 + (size_t)m*65536) : (G2T + (size_t)(m-256)*65536);
  int tid=threadIdx.x;
  float ss=0;
  for (int idx=tid; idx<65536; idx+=512){ float v=t[idx]; ss+=v*v; }
  #pragma unroll
  for (int o=32;o>0;o>>=1) ss += __shfl_down(ss, o, 64);
  __shared__ float wsum[8];
  int wid=tid>>6, lid=tid&63;
  if (lid==0) wsum[wid]=ss;
  __syncthreads();
  float tot=0;
  #pragma unroll
  for (int w=0;w<8;w++) tot+=wsum[w];
  float scale = 1.0f/fmaxf(sqrtf(tot), 1e-7f);
  for (int idx=tid; idx<65536; idx+=512) t[idx]*=scale;
}

__global__ __launch_bounds__(512) void k_ns_a(const float* __restrict__ G1, const float* __restrict__ G2T,
                                              float* __restrict__ ABM){
  int m=blockIdx.x;
  const float* t = (m<256)? (G1 + (size_t)m*65536) : (G2T + (size_t)(m-256)*65536);
  float* A = ABM + (size_t)m*16384;
  __shared__ float ts[128][33];
  int tid=threadIdx.x;
  int ig=tid>>4, jg=tid&15;
  int i0=ig*4, j0=jg*8;
  float acc[4][8]={};
  for (int k0=0;k0<512;k0+=32){
    for (int idx=tid; idx<4096; idx+=512){
      int r=idx>>5, kk=idx&31;
      ts[r][kk]=t[(size_t)r*512 + k0+kk];
    }
    __syncthreads();
    #pragma unroll 4
    for (int kk=0;kk<32;kk++){
      float iv[4], jv[8];
      #pragma unroll
      for (int i=0;i<4;i++) iv[i]=ts[i0+i][kk];
      #pragma unroll
      for (int j=0;j<8;j++) jv[j]=ts[j0+j][kk];
      #pragma unroll
      for (int i=0;i<4;i++)
        #pragma unroll
        for (int j=0;j<8;j++) acc[i][j]+=iv[i]*jv[j];
    }
    __syncthreads();
  }
  for (int i=0;i<4;i++)
    #pragma unroll
    for (int j=0;j<8;j++) A[(size_t)(i0+i)*128 + j0+j]=acc[i][j];
}

// t' = a*t + b*(A t) + c*A*(A t), per 32-col strip, in-place
__global__ __launch_bounds__(256) void k_ns_t(float* __restrict__ G1, float* __restrict__ G2T,
                                              const float* __restrict__ ABM){
  int blk=blockIdx.x, m=blk>>4, strip=blk&15, n0=strip*32;
  float* t = (m<256)? (G1 + (size_t)m*65536) : (G2T + (size_t)(m-256)*65536);
  const float* A = ABM + (size_t)m*16384;
  __shared__ float ts[128][33];
  __shared__ float asb[128][33];
  __shared__ float ps[128][33];
  int tid=threadIdx.x;
  for (int idx=tid; idx<4096; idx+=256){
    int r=idx>>5, nn=idx&31;
    ts[r][nn]=t[(size_t)r*512 + n0+nn];
  }
  int ig=tid>>3, ng=tid&7;
  int i0=ig*4, nn0=ng*4;
  float p[4][4]={};
  for (int k0=0;k0<128;k0+=32){
    for (int idx=tid; idx<4096; idx+=256){
      int r=idx>>5, kk=idx&31;
      asb[r][kk]=A[(size_t)r*128 + k0+kk];
    }
    __syncthreads();
    #pragma unroll 4
    for (int kk=0;kk<32;kk++){
      float av[4], tv[4];
      #pragma unroll
      for (int i=0;i<4;i++) av[i]=asb[i0+i][kk];
      #pragma unroll
      for (int j=0;j<4;j++) tv[j]=ts[k0+kk][nn0+j];
      #pragma unroll
      for (int i=0;i<4;i++)
        #pragma unroll
        for (int j=0;j<4;j++) p[i][j]+=av[i]*tv[j];
    }
    __syncthreads();
  }
  for (int i=0;i<4;i++)
    for (int j=0;j<4;j++) ps[i0+i][nn0+j]=p[i][j];
  __syncthreads();
  float ap[4][4]={};
  for (int k0=0;k0<128;k0+=32){
    for (int idx=tid; idx<4096; idx+=256){
      int r=idx>>5, kk=idx&31;
      asb[r][kk]=A[(size_t)r*128 + k0+kk];
    }
    __syncthreads();
    #pragma unroll 4
    for (int kk=0;kk<32;kk++){
      float av[4], pv[4];
      #pragma unroll
      for (int i=0;i<4;i++) av[i]=asb[i0+i][kk];
      #pragma unroll
      for (int j=0;j<4;j++) pv[j]=ps[k0+kk][nn0+j];
      #pragma unroll
      for (int i=0;i<4;i++)
        #pragma unroll
        for (int j=0;j<4;j++) ap[i][j]+=av[i]*pv[j];
    }
    __syncthreads();
  }
  const float CA=3.4445f, CB=-4.775f, CC=2.0315f;
  for (int i=0;i<4;i++)
    #pragma unroll
    for (int j=0;j<4;j++)
      t[(size_t)(i0+i)*512 + n0+nn0+j] = CA*ts[i0+i][nn0+j] + CB*p[i][j] + CC*ap[i][j];
}

// ---------------- momentum + decay scans (in-place), per (b,h) strand ----------------
__global__ __launch_bounds__(256) void k_scan_mat(float* __restrict__ G, const float* __restrict__ mw,
    const float* __restrict__ MOMb, const float* __restrict__ DECb, int transposed){
  int bh = blockIdx.x>>8;
  int eblk = blockIdx.x&255;
  int e = eblk*256 + threadIdx.x;
  int h = bh&3;
  float u;
  if (transposed){ int d = e>>9; int j = e&511; u = mw[(size_t)h*65536 + (size_t)j*128 + d]; }
  else u = mw[(size_t)h*65536 + e];
  float mval=0;
  for (int ci=0;ci<32;ci++){
    size_t off = ((size_t)(bh*32+ci))*65536 + e;
    float s = G[off];
    float mo = MOMb[bh*32+ci], de = DECb[bh*32+ci];
    mval = mo*mval + s;
    u = (1.0f-de)*u + mval;
    G[off]=u;
  }
}

__global__ __launch_bounds__(128) void k_scan_gamma(float* __restrict__ GG, const float* __restrict__ mg,
    const float* __restrict__ MOMb, const float* __restrict__ DECb){
  int bh=blockIdx.x; int e=threadIdx.x; int h=bh&3;
  float u = mg[h*128+e]; float mval=0;
  for (int ci=0;ci<32;ci++){
    size_t off = ((size_t)(bh*32+ci))*128 + e;
    float s = GG[off];
    float mo = MOMb[bh*32+ci], de = DECb[bh*32+ci];
    mval = mo*mval + s;
    u = (1.0f-de)*u + mval;
    GG[off]=u;
  }
}

// ---------------- retrieval: mem_forward with shifted weights, gated ----------------
__global__ __launch_bounds__(512) void k_retr(const float* __restrict__ Qb, const float* __restrict__ G1,
   const float* __restrict__ G2T, const float* __restrict__ GG, const float* __restrict__ mw1,
   const float* __restrict__ mw2, const float* __restrict__ mgamma,
   const float* __restrict__ GATEb, float* __restrict__ OUTT){
  int inst = blockIdx.x;
  int ci = inst & 31, h = (inst>>5)&3, b = inst>>7;
  size_t tok0 = (size_t)b*NN_ + (size_t)ci*64;
  int tid = threadIdx.x;
  __shared__ float qs[64][129];
  __shared__ float wbuf[4224];
  __shared__ float as_[64][33];
  __shared__ float red[64][17];
  __shared__ float rr[64];
  #define W1S(d,j) wbuf[(d)*33+(j)]
  #define W2S(j,d) wbuf[(j)*130+(d)]
  for (int idx=tid; idx<8192; idx+=512){
    int t = idx>>7, d = idx&127;
    qs[t][d] = Qb[(tok0+t)*512 + h*128 + d];
  }
  __syncthreads();
  int tg=tid>>4, dq=tid&15; int t0=tg*2, d0=dq*8;
  float h2a[2][8]={};
  const int first = (ci==0);
  const float* w1p = G1 + (size_t)(inst-1)*65536;
  const float* w2p = G2T + (size_t)(inst-1)*65536;
  for (int jt=0;jt<16;jt++){
    int j0=jt*32;
    if (first){
      for (int idx=tid; idx<4096; idx+=512){
        int d=idx>>5, jj=idx&31;
        W1S(d,jj)=mw1[(size_t)h*65536 + (size_t)d*512 + (j0+jj)];
      }
    } else {
      for (int idx=tid; idx<4096; idx+=512){
        int d=idx>>5, jj=idx&31;
        W1S(d,jj)=w1p[(size_t)d*512 + (j0+jj)];
      }
    }
    __syncthreads();
    {
      int jj0=dq*2;
      float a00=0,a01=0,a10=0,a11=0;
      for (int d=0;d<128;d++){
        float x0=qs[t0][d], x1=qs[t0+1][d];
        float w0=W1S(d,jj0), w1v=W1S(d,jj0+1);
        a00+=x0*w0; a01+=x0*w1v; a10+=x1*w0; a11+=x1*w1v;
      }
      as_[t0][jj0]=geluf(a00);   as_[t0][jj0+1]=geluf(a01);
      as_[t0+1][jj0]=geluf(a10); as_[t0+1][jj0+1]=geluf(a11);
    }
    __syncthreads();
    if (first){
      for (int idx=tid; idx<4096; idx+=512){
        int jj=idx>>7, d=idx&127;
        W2S(jj,d)=mw2[(size_t)h*65536 + (size_t)(j0+jj)*128 + d];
      }
    } else {
      for (int idx=tid; idx<4096; idx+=512){
        int d=idx>>5, jj=idx&31;
        W2S(jj,d)=w2p[(size_t)d*512 + (j0+jj)];
      }
    }
    __syncthreads();
    for (int jj=0;jj<32;jj++){
      float a0=as_[t0][jj], a1=as_[t0+1][jj];
      #pragma unroll
      for (int j2=0;j2<8;j2++){
        float wv=W2S(jj,d0+j2);
        h2a[0][j2]+=a0*wv; h2a[1][j2]+=a1*wv;
      }
    }
    __syncthreads();
  }
  float ss0=0, ss1=0;
  #pragma unroll
  for (int j=0;j<8;j++){ ss0+=h2a[0][j]*h2a[0][j]; ss1+=h2a[1][j]*h2a[1][j]; }
  red[t0][dq]=ss0; red[t0+1][dq]=ss1;
  __syncthreads();
  if (tid<64){
    float s=0;
    #pragma unroll
    for (int q=0;q<16;q++) s+=red[tid][q];
    rr[tid]=rsqrtf(s*(1.0f/128.0f)+1e-6f);
  }
  __syncthreads();
  for (int i=0;i<2;i++){
    int t=t0+i; float r=rr[t];
    float gate = GATEb[(tok0+t)*4+h];
    #pragma unroll
    for (int j=0;j<8;j++){
      int d=d0+j;
      float gv = first? mgamma[h*128+d] : GG[(size_t)(inst-1)*128+d];
      OUTT[(tok0+t)*512 + h*128 + d] = (h2a[i][j]*r*gv + qs[t][d])*gate;
    }
  }
  #undef W1S
  #undef W2S
}

extern "C" void kernel_launch(void* const* d_in, const int* in_sizes, int n_in,
                              void* d_out, int out_size, void* d_ws, size_t ws_size,
                              hipStream_t stream) {
  (void)in_sizes; (void)n_in; (void)out_size; (void)ws_size;
  const float* seq   = (const float*)d_in[0];
  const float* sg    = (const float*)d_in[1];
  const float* rg    = (const float*)d_in[2];
  const float* Wq    = (const float*)d_in[3];
  const float* Wk    = (const float*)d_in[4];
  const float* Wv    = (const float*)d_in[5];
  const float* Wlr   = (const float*)d_in[6];
  const float* blr   = (const float*)d_in[7];
  const float* Wm    = (const float*)d_in[8];
  const float* bm    = (const float*)d_in[9];
  const float* Wd    = (const float*)d_in[10];
  const float* bd    = (const float*)d_in[11];
  const float* Wgate = (const float*)d_in[12];
  const float* Wc    = (const float*)d_in[13];
  const float* mw1   = (const float*)d_in[14];
  const float* mw2   = (const float*)d_in[15];
  const float* mgam  = (const float*)d_in[16];

  float* W = (float*)d_ws;
  float* S    = W + 0;
  float* SR   = W + 2097152;
  float* Kb   = W + 4194304;
  float* Vb   = W + 6291456;
  float* H1B  = W + 8388608;
  float* DH2  = W + 16777216;
  float* Qb   = W + 18874368;
  float* LRb  = W + 20971520;
  float* GATEb= W + 20987904;
  float* MOMb = W + 21004288;
  float* DECb = W + 21004544;
  float* GGb  = W + 21004800;
  float* G1   = W + 21037568;
  float* G2T  = W + 37814784;
  float* ABM  = W + 0;        // overlay (S..Vb free by NS time): 512*16384 floats
  float* OUTT = W + 8388608;  // overlay H1B slot (free by retrieval time)

  k_rmsnorm<<<4096,256,0,stream>>>(seq, sg, rg, S, SR);
  dim3 gg(64,8);
  k_gemm<<<gg,256,0,stream>>>(S,  Wk, Kb);
  k_gemm<<<gg,256,0,stream>>>(S,  Wv, Vb);
  k_gemm<<<gg,256,0,stream>>>(SR, Wq, Qb);
  k_small<<<64,256,0,stream>>>(S, SR, Wlr, blr, Wm, bm, Wd, bd, Wgate, LRb, GATEb, MOMb, DECb);
  k_fwd<<<256,512,0,stream>>>(Kb, Vb, LRb, mw1, mw2, mgam, H1B, DH2, GGb);
  k_dw2<<<2048,256,0,stream>>>(H1B, DH2, G2T);
  k_dw1<<<4096,256,0,stream>>>(Kb, DH2, H1B, mw2, G1);
  k_ns_prep<<<512,512,0,stream>>>(G1, G2T);
  for (int it=0; it<5; it++){
    k_ns_a<<<512,512,0,stream>>>(G1, G2T, ABM);
    k_ns_t<<<8192,256,0,stream>>>(G1, G2T, ABM);
  }
  k_scan_mat<<<2048,256,0,stream>>>(G1,  mw1, MOMb, DECb, 0);
  k_scan_mat<<<2048,256,0,stream>>>(G2T, mw2, MOMb, DECb, 1);
  k_scan_gamma<<<8,128,0,stream>>>(GGb, mgam, MOMb, DECb);
  k_retr<<<256,512,0,stream>>>(Qb, G1, G2T, GGb, mw1, mw2, mgam, GATEb, OUTT);
  k_gemm<<<gg,256,0,stream>>>(OUTT, Wc, (float*)d_out);
}

// Round 4
// 1816.755 us; speedup vs baseline: 2.2667x; 2.2667x over previous
//
#include <hip/hip_runtime.h>
#include <hip/hip_bf16.h>
#include <math.h>

#define NN_ 2048

typedef short v8s __attribute__((ext_vector_type(8)));
typedef float v4f __attribute__((ext_vector_type(4)));

__device__ __forceinline__ float geluf(float x){ return 0.5f*x*(1.0f+erff(x*0.70710678118654752440f)); }
__device__ __forceinline__ float gelupf(float x){
  float cdf = 0.5f*(1.0f+erff(x*0.70710678118654752440f));
  float pdf = 0.39894228040143267794f*expf(-0.5f*x*x);
  return cdf + x*pdf;
}
__device__ __forceinline__ float sigm(float x){ return 1.0f/(1.0f+expf(-x)); }

__device__ __forceinline__ unsigned short f2bs(float f){
  __hip_bfloat16 h = __float2bfloat16(f);
  return __builtin_bit_cast(unsigned short, h);
}
__device__ __forceinline__ float bs2f(unsigned short u){
  unsigned v = ((unsigned)u)<<16;
  return __builtin_bit_cast(float, v);
}
// XOR-swizzled index into a 128-wide bf16 LDS tile (16B blocks xor'd by row)
__device__ __forceinline__ int swz(int r, int k){
  return r*128 + ((((k>>3) ^ (r&15)) & 15)<<3) + (k&7);
}
// 64-wide variant
__device__ __forceinline__ int swz64(int r, int k){
  return r*64 + ((((k>>3) ^ (r&7)) & 7)<<3) + (k&7);
}

// ---------------- rmsnorm of seq with store/retrieve gains ----------------
__global__ __launch_bounds__(256) void k_rmsnorm(const float* __restrict__ seq, const float* __restrict__ gs,
                          const float* __restrict__ gr, float* __restrict__ S, float* __restrict__ SR){
  int tok = blockIdx.x;
  const float* row = seq + (size_t)tok*512;
  int tid = threadIdx.x;
  float x0 = row[tid];
  float x1 = row[tid+256];
  float ss = x0*x0 + x1*x1;
  #pragma unroll
  for (int o=32;o>0;o>>=1) ss += __shfl_down(ss, o, 64);
  __shared__ float wsum[4];
  int wid = tid>>6, lid = tid&63;
  if (lid==0) wsum[wid]=ss;
  __syncthreads();
  float tot = wsum[0]+wsum[1]+wsum[2]+wsum[3];
  float r = rsqrtf(tot*(1.0f/512.0f) + 1e-6f);
  size_t o0 = (size_t)tok*512 + tid;
  S[o0]      = x0*r*gs[tid];
  S[o0+256]  = x1*r*gs[tid+256];
  SR[o0]     = x0*r*gr[tid];
  SR[o0+256] = x1*r*gr[tid+256];
}

// ---------------- generic tiled GEMM: (4096x512 f32) @ (512x512 f32) ----------------
__global__ __launch_bounds__(256) void k_gemm(const float* __restrict__ X, const float* __restrict__ Wt,
                       float* __restrict__ O){
  __shared__ float Xs[64][33];
  __shared__ float Ws[32][65];
  int rt = blockIdx.x, ct = blockIdx.y, tid = threadIdx.x;
  int r0 = (tid>>4)*4, c0 = (tid&15)*4;
  float acc[4][4] = {};
  for (int k0=0;k0<512;k0+=32){
    for (int idx=tid; idx<2048; idx+=256){
      int r = idx>>5, kk = idx&31;
      Xs[r][kk] = X[(size_t)(rt*64+r)*512 + (k0+kk)];
    }
    for (int idx=tid; idx<2048; idx+=256){
      int kk = idx>>6, c = idx&63;
      Ws[kk][c] = Wt[(size_t)(k0+kk)*512 + (ct*64+c)];
    }
    __syncthreads();
    #pragma unroll 8
    for (int kk=0;kk<32;kk++){
      float xv[4], wv[4];
      #pragma unroll
      for (int i=0;i<4;i++) xv[i]=Xs[r0+i][kk];
      #pragma unroll
      for (int j=0;j<4;j++) wv[j]=Ws[kk][c0+j];
      #pragma unroll
      for (int i=0;i<4;i++)
        #pragma unroll
        for (int j=0;j<4;j++) acc[i][j] += xv[i]*wv[j];
    }
    __syncthreads();
  }
  for (int i=0;i<4;i++)
    for (int j=0;j<4;j++){
      size_t row = (size_t)rt*64+r0+i, col = (size_t)ct*64+c0+j;
      O[row*512+col] = acc[i][j];
    }
}

// ---------------- lr/gate per token, pooled->mom/dec per chunk ----------------
__global__ __launch_bounds__(256) void k_small(const float* __restrict__ S, const float* __restrict__ SR,
    const float* __restrict__ Wlr, const float* __restrict__ blr, const float* __restrict__ Wm,
    const float* __restrict__ bm, const float* __restrict__ Wd, const float* __restrict__ bd,
    const float* __restrict__ Wgate,
    float* __restrict__ LRb, float* __restrict__ GATEb, float* __restrict__ MOMb, float* __restrict__ DECb){
  int bc = blockIdx.x;            // b*32 + ci
  int b = bc>>5, ci = bc&31;
  int tid = threadIdx.x;
  int t = tid>>2, h = tid&3;
  size_t tokbase = (size_t)b*NN_ + (size_t)ci*64;
  __shared__ float pool[512];
  for (int c=tid; c<512; c+=256){
    float s=0;
    for (int t2=0;t2<64;t2++) s += S[(tokbase+t2)*512 + c];
    pool[c] = s*(1.0f/64.0f);
  }
  size_t tok = tokbase + t;
  const float* srow = S + tok*512;
  const float* srrow = SR + tok*512;
  float accl=0, accg=0;
  for (int d=0; d<512; d++){
    accl += srow[d]*Wlr[d*4+h];
    accg += srrow[d]*Wgate[d*4+h];
  }
  accl += blr[h];
  LRb[tok*4+h] = sigm(accl);
  GATEb[tok*4+h] = sigm(accg);
  __syncthreads();
  if (tid<8){
    int hh = tid&3, which = tid>>2;
    float a=0;
    const float* Wx = which? Wd : Wm;
    for (int d=0; d<512; d++) a += pool[d]*Wx[d*4+hh];
    a += which? bd[hh] : bm[hh];
    float v = sigm(a);
    size_t o = ((size_t)b*4+hh)*32 + ci;
    if (which) DECb[o]=v; else MOMb[o]=v;
  }
}

// ---------------- fused memory-MLP forward + rmsnorm backward (per chunk) ----------------
__global__ __launch_bounds__(512) void k_fwd(const float* __restrict__ Kb, const float* __restrict__ Vb,
    const float* __restrict__ LRb, const float* __restrict__ mw1, const float* __restrict__ mw2,
    const float* __restrict__ mgamma, float* __restrict__ H1B, float* __restrict__ DH2,
    float* __restrict__ GG){
  int inst = blockIdx.x;
  int ci = inst & 31, h = (inst>>5)&3, b = inst>>7;
  size_t tok0 = (size_t)b*NN_ + (size_t)ci*64;
  int tid = threadIdx.x;
  __shared__ float xs[64][129];
  __shared__ float wbuf[4224];
  __shared__ float as_[64][33];
  __shared__ float red[64][17];
  __shared__ float sgg[128];
  __shared__ float rr[64], lrs[64], dotl[64];
  #define W1S(d,j) wbuf[(d)*33+(j)]
  #define W2S(j,d) wbuf[(j)*130+(d)]
  for (int idx=tid; idx<8192; idx+=512){
    int t = idx>>7, d = idx&127;
    xs[t][d] = Kb[(tok0+t)*512 + h*128 + d];
  }
  if (tid<64) lrs[tid] = LRb[(tok0+tid)*4 + h];
  if (tid<128) sgg[tid]=0.0f;
  __syncthreads();
  int tg = tid>>4, dq = tid&15;
  int t0 = tg*2, d0 = dq*8;
  float h2a[2][8] = {};
  for (int jt=0;jt<16;jt++){
    int j0 = jt*32;
    for (int idx=tid; idx<4096; idx+=512){
      int d = idx>>5, jj = idx&31;
      W1S(d,jj) = mw1[(size_t)h*65536 + (size_t)d*512 + (j0+jj)];
    }
    __syncthreads();
    {
      int jj0 = dq*2;
      float a00=0,a01=0,a10=0,a11=0;
      for (int d=0; d<128; d++){
        float x0=xs[t0][d], x1=xs[t0+1][d];
        float w0=W1S(d,jj0), w1v=W1S(d,jj0+1);
        a00+=x0*w0; a01+=x0*w1v; a10+=x1*w0; a11+=x1*w1v;
      }
      size_t hb = (size_t)inst*32768;
      H1B[hb + (size_t)t0*512 + j0+jj0]       = a00;
      H1B[hb + (size_t)t0*512 + j0+jj0+1]     = a01;
      H1B[hb + (size_t)(t0+1)*512 + j0+jj0]   = a10;
      H1B[hb + (size_t)(t0+1)*512 + j0+jj0+1] = a11;
      as_[t0][jj0]=geluf(a00);   as_[t0][jj0+1]=geluf(a01);
      as_[t0+1][jj0]=geluf(a10); as_[t0+1][jj0+1]=geluf(a11);
    }
    __syncthreads();
    for (int idx=tid; idx<4096; idx+=512){
      int jj = idx>>7, d = idx&127;
      W2S(jj,d) = mw2[(size_t)h*65536 + (size_t)(j0+jj)*128 + d];
    }
    __syncthreads();
    for (int jj=0;jj<32;jj++){
      float a0=as_[t0][jj], a1=as_[t0+1][jj];
      #pragma unroll
      for (int j2=0;j2<8;j2++){
        float wv = W2S(jj, d0+j2);
        h2a[0][j2]+=a0*wv; h2a[1][j2]+=a1*wv;
      }
    }
    __syncthreads();
  }
  float ss0=0, ss1=0;
  #pragma unroll
  for (int j=0;j<8;j++){ ss0+=h2a[0][j]*h2a[0][j]; ss1+=h2a[1][j]*h2a[1][j]; }
  red[t0][dq]=ss0; red[t0+1][dq]=ss1;
  __syncthreads();
  if (tid<64){
    float s=0;
    #pragma unroll
    for (int q=0;q<16;q++) s+=red[tid][q];
    rr[tid] = rsqrtf(s*(1.0f/128.0f) + 1e-6f);
  }
  __syncthreads();
  float dn[2][8]; float dot0=0, dot1=0; float ggp[8]={};
  for (int i=0;i<2;i++){
    int t=t0+i;
    float r = rr[t];
    float lrv = lrs[t]*(2.0f/128.0f);
    #pragma unroll
    for (int j=0;j<8;j++){
      int d = d0+j;
      float nval = h2a[i][j]*r;
      float gv = mgamma[h*128+d];
      float pred = nval*gv + xs[t][d];
      float dp = lrv*(pred - Vb[(tok0+t)*512 + h*128 + d]);
      ggp[j] += dp*nval;
      float dnv = dp*gv;
      dn[i][j]=dnv;
      if (i==0) dot0 += dnv*h2a[i][j]; else dot1 += dnv*h2a[i][j];
    }
  }
  #pragma unroll
  for (int j=0;j<8;j++) atomicAdd(&sgg[d0+j], ggp[j]);
  red[t0][dq]=dot0; red[t0+1][dq]=dot1;
  __syncthreads();
  if (tid<64){
    float s=0;
    #pragma unroll
    for (int q=0;q<16;q++) s+=red[tid][q];
    dotl[tid]=s;
  }
  __syncthreads();
  for (int i=0;i<2;i++){
    int t=t0+i; float r=rr[t];
    float dt = dotl[t]*r*r*r*(1.0f/128.0f);
    #pragma unroll
    for (int j=0;j<8;j++)
      DH2[(size_t)inst*8192 + (size_t)t*128 + d0+j] = r*dn[i][j] - dt*h2a[i][j];
  }
  if (tid<128) GG[(size_t)inst*128+tid] = -sgg[tid];
  #undef W1S
  #undef W2S
}

// ---------------- G2T[d][j] = -sum_t gelu(h1[t,j]) * dh2[t,d]  ----------------
__global__ __launch_bounds__(256) void k_dw2(const float* __restrict__ H1B, const float* __restrict__ DH2,
                      float* __restrict__ G2T){
  int inst = blockIdx.x>>3;
  int jt = blockIdx.x&7; int j0 = jt*64;
  int tid = threadIdx.x;
  __shared__ float dh2s[64][129];
  __shared__ float as2[64][65];
  for (int idx=tid; idx<8192; idx+=256){ int t=idx>>7, d=idx&127; dh2s[t][d]=DH2[(size_t)inst*8192+idx]; }
  for (int idx=tid; idx<4096; idx+=256){ int t=idx>>6, jj=idx&63; as2[t][jj]=geluf(H1B[(size_t)inst*32768+(size_t)t*512+j0+jj]); }
  __syncthreads();
  int dg=tid>>3, jg=tid&7; int d0=dg*4, jj0=jg*8;
  float acc[4][8]={};
  for (int t=0;t<64;t++){
    float dv[4], av[8];
    #pragma unroll
    for (int i=0;i<4;i++) dv[i]=dh2s[t][d0+i];
    #pragma unroll
    for (int j=0;j<8;j++) av[j]=as2[t][jj0+j];
    #pragma unroll
    for (int i=0;i<4;i++)
      #pragma unroll
      for (int j=0;j<8;j++) acc[i][j]+=av[j]*dv[i];
  }
  for (int i=0;i<4;i++)
    #pragma unroll
    for (int j=0;j<8;j++)
      G2T[(size_t)inst*65536 + (size_t)(d0+i)*512 + j0+jj0+j] = -acc[i][j];
}

// ---------------- da = dh2 @ w2^T ; dh1 = da*gelu'(h1); G1 = -x^T @ dh1 ----------------
__global__ __launch_bounds__(256) void k_dw1(const float* __restrict__ Kb, const float* __restrict__ DH2,
    const float* __restrict__ H1B, const float* __restrict__ mw2, float* __restrict__ G1){
  int inst = blockIdx.x>>4; int jt = blockIdx.x&15; int j0=jt*32;
  int ci = inst&31, h=(inst>>5)&3, b=inst>>7;
  size_t tok0 = (size_t)b*NN_ + (size_t)ci*64;
  int tid=threadIdx.x;
  __shared__ float buf[64][129];
  __shared__ float w2s[32][130];
  __shared__ float dh1s[64][33];
  for (int idx=tid; idx<8192; idx+=256){ int t=idx>>7, d=idx&127; buf[t][d]=DH2[(size_t)inst*8192+idx]; }
  for (int idx=tid; idx<4096; idx+=256){ int jj=idx>>7, d=idx&127; w2s[jj][d]=mw2[(size_t)h*65536+(size_t)(j0+jj)*128+d]; }
  __syncthreads();
  int tg=tid>>3, jg=tid&7; int t0=tg*2, jj0=jg*4;
  float da[2][4]={};
  for (int d=0; d<128; d++){
    float q0=buf[t0][d], q1=buf[t0+1][d];
    #pragma unroll
    for (int j=0;j<4;j++){ float wv=w2s[jj0+j][d]; da[0][j]+=q0*wv; da[1][j]+=q1*wv; }
  }
  float dh1v[2][4];
  for (int i=0;i<2;i++)
    for (int j=0;j<4;j++){
      float hv = H1B[(size_t)inst*32768 + (size_t)(t0+i)*512 + j0+jj0+j];
      dh1v[i][j] = da[i][j]*gelupf(hv);
    }
  __syncthreads();
  for (int i=0;i<2;i++)
    for (int j=0;j<4;j++) dh1s[t0+i][jj0+j]=dh1v[i][j];
  for (int idx=tid; idx<8192; idx+=256){ int t=idx>>7, d=idx&127; buf[t][d]=Kb[(tok0+t)*512 + h*128 + d]; }
  __syncthreads();
  int dg=tid>>3; int d0=dg*4;
  float acc[4][4]={};
  for (int t=0;t<64;t++){
    float xv[4], hv[4];
    #pragma unroll
    for (int i=0;i<4;i++) xv[i]=buf[t][d0+i];
    #pragma unroll
    for (int j=0;j<4;j++) hv[j]=dh1s[t][jj0+j];
    #pragma unroll
    for (int i=0;i<4;i++)
      #pragma unroll
      for (int j=0;j<4;j++) acc[i][j]+=xv[i]*hv[j];
  }
  for (int i=0;i<4;i++)
    for (int j=0;j<4;j++)
      G1[(size_t)inst*65536 + (size_t)(d0+i)*512 + j0+jj0+j] = -acc[i][j];
}

// ---------------- NS prep: Frobenius-normalize each 128x512 matrix in place (fp32) ----------------
__global__ __launch_bounds__(512) void k_ns_prep(float* __restrict__ G1, float* __restrict__ G2T){
  int m = blockIdx.x;
  float* t = (m<256)? (G1 + (size_t)m*65536) : (G2T + (size_t)(m-256)*65536);
  int tid=threadIdx.x;
  float ss=0;
  for (int idx=tid; idx<65536; idx+=512){ float v=t[idx]; ss+=v*v; }
  #pragma unroll
  for (int o=32;o>0;o>>=1) ss += __shfl_down(ss, o, 64);
  __shared__ float wsum[8];
  int wid=tid>>6, lid=tid&63;
  if (lid==0) wsum[wid]=ss;
  __syncthreads();
  float tot=0;
  #pragma unroll
  for (int w=0;w<8;w++) tot+=wsum[w];
  float scale = 1.0f/fmaxf(sqrtf(tot), 1e-7f);
  for (int idx=tid; idx<65536; idx+=512) t[idx]*=scale;
}

// ---------------- NS step 1: A = t@t^T, split -> ABh/ABl (bf16 planes) ----------------
__global__ __launch_bounds__(256) void k_nsA(const float* __restrict__ G1, const float* __restrict__ G2T,
                                             unsigned short* __restrict__ ABh, unsigned short* __restrict__ ABl){
  int m = blockIdx.x;
  const float* t = (m<256)? (G1 + (size_t)m*65536) : (G2T + (size_t)(m-256)*65536);
  __shared__ unsigned short th[16384];   // t chunk hi, swizzled
  __shared__ unsigned short tl[16384];   // t chunk lo, swizzled
  int tid = threadIdx.x;
  int w = tid>>6, lane = tid&63;
  int n = lane&15, quad = lane>>4;
  v4f acc[2][8];
  #pragma unroll
  for (int i=0;i<2;i++)
    #pragma unroll
    for (int j=0;j<8;j++){ v4f z = {0.f,0.f,0.f,0.f}; acc[i][j]=z; }
  for (int c=0;c<4;c++){
    int k0 = c*128;
    for (int it=0; it<16; it++){
      int idx = it*1024 + tid*4;
      int r = idx>>7, k = idx&127;
      float4 v = *(const float4*)(t + (size_t)r*512 + k0 + k);
      union { unsigned long long q; unsigned short s[4]; } uh, ulw;
      uh.s[0]=f2bs(v.x); uh.s[1]=f2bs(v.y); uh.s[2]=f2bs(v.z); uh.s[3]=f2bs(v.w);
      ulw.s[0]=f2bs(v.x-bs2f(uh.s[0])); ulw.s[1]=f2bs(v.y-bs2f(uh.s[1]));
      ulw.s[2]=f2bs(v.z-bs2f(uh.s[2])); ulw.s[3]=f2bs(v.w-bs2f(uh.s[3]));
      *(unsigned long long*)&th[swz(r,k)] = uh.q;
      *(unsigned long long*)&tl[swz(r,k)] = ulw.q;
    }
    __syncthreads();
    for (int kk=0; kk<128; kk+=32){
      int kf = kk + quad*8;
      v8s ah[2], al[2], bh[8], bl[8];
      #pragma unroll
      for (int i=0;i<2;i++){ int r = w*32 + i*16 + n; ah[i]=*(const v8s*)&th[swz(r,kf)]; al[i]=*(const v8s*)&tl[swz(r,kf)]; }
      #pragma unroll
      for (int j=0;j<8;j++){ int r = j*16 + n; bh[j]=*(const v8s*)&th[swz(r,kf)]; bl[j]=*(const v8s*)&tl[swz(r,kf)]; }
      #pragma unroll
      for (int i=0;i<2;i++)
        #pragma unroll
        for (int j=0;j<8;j++){
          acc[i][j] = __builtin_amdgcn_mfma_f32_16x16x32_bf16(ah[i], bh[j], acc[i][j], 0,0,0);
          acc[i][j] = __builtin_amdgcn_mfma_f32_16x16x32_bf16(ah[i], bl[j], acc[i][j], 0,0,0);
          acc[i][j] = __builtin_amdgcn_mfma_f32_16x16x32_bf16(al[i], bh[j], acc[i][j], 0,0,0);
        }
    }
    __syncthreads();
  }
  // split A -> plain row-major staging -> coalesced global store
  #pragma unroll
  for (int i=0;i<2;i++)
    #pragma unroll
    for (int j=0;j<8;j++)
      #pragma unroll
      for (int r=0;r<4;r++){
        int row = w*32 + i*16 + quad*4 + r;
        int col = j*16 + n;
        float v = acc[i][j][r];
        unsigned short hs = f2bs(v);
        th[row*128+col] = hs;
        tl[row*128+col] = f2bs(v - bs2f(hs));
      }
  __syncthreads();
  for (int it=0; it<8; it++){
    int idx = it*2048 + tid*8;
    *(v8s*)&ABh[(size_t)m*16384 + idx] = *(const v8s*)&th[idx];
    *(v8s*)&ABl[(size_t)m*16384 + idx] = *(const v8s*)&tl[idx];
  }
}

// ---------------- NS step 2: B = b*A + c*A@A, split, in-place over AB planes ----------------
__global__ __launch_bounds__(256) void k_nsB(unsigned short* __restrict__ ABh, unsigned short* __restrict__ ABl){
  int m = blockIdx.x;
  __shared__ unsigned short Ah[16384];
  __shared__ unsigned short Al[16384];
  int tid = threadIdx.x;
  int w = tid>>6, lane = tid&63;
  int n = lane&15, quad = lane>>4;
  for (int it=0; it<8; it++){
    int idx = it*2048 + tid*8;
    int r = idx>>7, k = idx&127;
    *(v8s*)&Ah[swz(r,k)] = *(const v8s*)&ABh[(size_t)m*16384 + idx];
    *(v8s*)&Al[swz(r,k)] = *(const v8s*)&ABl[(size_t)m*16384 + idx];
  }
  __syncthreads();
  v4f acc[2][8];
  #pragma unroll
  for (int i=0;i<2;i++)
    #pragma unroll
    for (int j=0;j<8;j++){ v4f z = {0.f,0.f,0.f,0.f}; acc[i][j]=z; }
  for (int kk=0; kk<128; kk+=32){
    int kf = kk + quad*8;
    v8s ah[2], al2[2], bh[8], bl[8];
    #pragma unroll
    for (int i=0;i<2;i++){ int r = w*32 + i*16 + n; ah[i]=*(const v8s*)&Ah[swz(r,kf)]; al2[i]=*(const v8s*)&Al[swz(r,kf)]; }
    #pragma unroll
    for (int j=0;j<8;j++){ int r = j*16 + n; bh[j]=*(const v8s*)&Ah[swz(r,kf)]; bl[j]=*(const v8s*)&Al[swz(r,kf)]; }
    #pragma unroll
    for (int i=0;i<2;i++)
      #pragma unroll
      for (int j=0;j<8;j++){
        acc[i][j] = __builtin_amdgcn_mfma_f32_16x16x32_bf16(ah[i], bh[j], acc[i][j], 0,0,0);
        acc[i][j] = __builtin_amdgcn_mfma_f32_16x16x32_bf16(ah[i], bl[j], acc[i][j], 0,0,0);
        acc[i][j] = __builtin_amdgcn_mfma_f32_16x16x32_bf16(al2[i], bh[j], acc[i][j], 0,0,0);
      }
  }
  // B = CB*A + CC*A2 at C positions (A fp32 = hi+lo read from LDS)
  const float CB=-4.775f, CC=2.0315f;
  float Bv[2][8][4];
  #pragma unroll
  for (int i=0;i<2;i++)
    #pragma unroll
    for (int j=0;j<8;j++)
      #pragma unroll
      for (int r=0;r<4;r++){
        int row = w*32 + i*16 + quad*4 + r;
        int col = j*16 + n;
        float av = bs2f(Ah[swz(row,col)]) + bs2f(Al[swz(row,col)]);
        Bv[i][j][r] = CB*av + CC*acc[i][j][r];
      }
  __syncthreads();
  #pragma unroll
  for (int i=0;i<2;i++)
    #pragma unroll
    for (int j=0;j<8;j++)
      #pragma unroll
      for (int r=0;r<4;r++){
        int row = w*32 + i*16 + quad*4 + r;
        int col = j*16 + n;
        float v = Bv[i][j][r];
        unsigned short hs = f2bs(v);
        Ah[row*128+col] = hs;
        Al[row*128+col] = f2bs(v - bs2f(hs));
      }
  __syncthreads();
  for (int it=0; it<8; it++){
    int idx = it*2048 + tid*8;
    *(v8s*)&ABh[(size_t)m*16384 + idx] = *(const v8s*)&Ah[idx];
    *(v8s*)&ABl[(size_t)m*16384 + idx] = *(const v8s*)&Al[idx];
  }
}

// ---------------- NS step 3: t' = a*t + B@t per 128-col strip (B symmetric), in place ----------------
__global__ __launch_bounds__(256) void k_nsZ(float* __restrict__ G1, float* __restrict__ G2T,
                                             const unsigned short* __restrict__ ABh, const unsigned short* __restrict__ ABl){
  int blk = blockIdx.x;
  int m = blk>>2, s = blk&3, c0 = s*128;
  float* t = (m<256)? (G1 + (size_t)m*65536) : (G2T + (size_t)(m-256)*65536);
  __shared__ __align__(16) unsigned char smem[65536];
  unsigned short* Bh = (unsigned short*)smem;        // [128][64] swizzled
  unsigned short* Bl = Bh + 8192;
  unsigned short* uh = Bh + 16384;                   // u[j][k] = t[k0+k][c0+j]
  unsigned short* ul = Bh + 24576;
  float* Zs = (float*)smem;                          // epilogue alias [128][128] fp32
  int tid = threadIdx.x;
  int w = tid>>6, lane = tid&63;
  int n = lane&15, quad = lane>>4;
  v4f acc[2][8];
  #pragma unroll
  for (int i=0;i<2;i++)
    #pragma unroll
    for (int j=0;j<8;j++){ v4f z = {0.f,0.f,0.f,0.f}; acc[i][j]=z; }
  for (int c=0;c<2;c++){
    int k0 = c*64;
    for (int it=0; it<4; it++){
      int idx = it*2048 + tid*8;
      int r = idx>>6, k = idx&63;
      *(v8s*)&Bh[swz64(r,k)] = *(const v8s*)&ABh[(size_t)m*16384 + (size_t)r*128 + k0 + k];
      *(v8s*)&Bl[swz64(r,k)] = *(const v8s*)&ABl[(size_t)m*16384 + (size_t)r*128 + k0 + k];
    }
    for (int it=0; it<8; it++){
      int idx = it*1024 + tid*4;
      int kr = idx>>7, j = idx&127;
      float4 v = *(const float4*)(t + (size_t)(k0+kr)*512 + c0 + j);
      float vv[4] = {v.x, v.y, v.z, v.w};
      #pragma unroll
      for (int e=0;e<4;e++){
        unsigned short hs = f2bs(vv[e]);
        uh[swz64(j+e, kr)] = hs;
        ul[swz64(j+e, kr)] = f2bs(vv[e] - bs2f(hs));
      }
    }
    __syncthreads();
    #pragma unroll
    for (int kk=0; kk<64; kk+=32){
      int kf = kk + quad*8;
      v8s ah[2], al2[2], bhf[8], blf[8];
      #pragma unroll
      for (int i=0;i<2;i++){ int r = w*32 + i*16 + n; ah[i]=*(const v8s*)&Bh[swz64(r,kf)]; al2[i]=*(const v8s*)&Bl[swz64(r,kf)]; }
      #pragma unroll
      for (int j=0;j<8;j++){ int r = j*16 + n; bhf[j]=*(const v8s*)&uh[swz64(r,kf)]; blf[j]=*(const v8s*)&ul[swz64(r,kf)]; }
      #pragma unroll
      for (int i=0;i<2;i++)
        #pragma unroll
        for (int j=0;j<8;j++){
          acc[i][j] = __builtin_amdgcn_mfma_f32_16x16x32_bf16(ah[i], bhf[j], acc[i][j], 0,0,0);
          acc[i][j] = __builtin_amdgcn_mfma_f32_16x16x32_bf16(ah[i], blf[j], acc[i][j], 0,0,0);
          acc[i][j] = __builtin_amdgcn_mfma_f32_16x16x32_bf16(al2[i], bhf[j], acc[i][j], 0,0,0);
        }
    }
    __syncthreads();
  }
  // stage Z fp32, then coalesced in-place update t' = a*t + Z
  #pragma unroll
  for (int i=0;i<2;i++)
    #pragma unroll
    for (int j=0;j<8;j++)
      #pragma unroll
      for (int r=0;r<4;r++){
        int row = w*32 + i*16 + quad*4 + r;  // Z row (t row)
        int col = j*16 + n;                  // strip col
        Zs[row*128+col] = acc[i][j][r];
      }
  __syncthreads();
  const float CA = 3.4445f;
  for (int it=0; it<16; it++){
    int idx = it*1024 + tid*4;
    int i = idx>>7, j = idx&127;
    float* dst = t + (size_t)i*512 + c0 + j;
    float4 told = *(const float4*)dst;
    float4 o;
    o.x = CA*told.x + Zs[i*128+j+0];
    o.y = CA*told.y + Zs[i*128+j+1];
    o.z = CA*told.z + Zs[i*128+j+2];
    o.w = CA*told.w + Zs[i*128+j+3];
    *(float4*)dst = o;
  }
}

// ---------------- momentum + decay scans (in-place), per (b,h) strand ----------------
__global__ __launch_bounds__(256) void k_scan_mat(float* __restrict__ G, const float* __restrict__ mw,
    const float* __restrict__ MOMb, const float* __restrict__ DECb, int transposed){
  int bh = blockIdx.x>>8;
  int eblk = blockIdx.x&255;
  int e = eblk*256 + threadIdx.x;
  int h = bh&3;
  float u;
  if (transposed){ int d = e>>9; int j = e&511; u = mw[(size_t)h*65536 + (size_t)j*128 + d]; }
  else u = mw[(size_t)h*65536 + e];
  float mval=0;
  for (int ci=0;ci<32;ci++){
    size_t off = ((size_t)(bh*32+ci))*65536 + e;
    float s = G[off];
    float mo = MOMb[bh*32+ci], de = DECb[bh*32+ci];
    mval = mo*mval + s;
    u = (1.0f-de)*u + mval;
    G[off]=u;
  }
}

__global__ __launch_bounds__(128) void k_scan_gamma(float* __restrict__ GG, const float* __restrict__ mg,
    const float* __restrict__ MOMb, const float* __restrict__ DECb){
  int bh=blockIdx.x; int e=threadIdx.x; int h=bh&3;
  float u = mg[h*128+e]; float mval=0;
  for (int ci=0;ci<32;ci++){
    size_t off = ((size_t)(bh*32+ci))*128 + e;
    float s = GG[off];
    float mo = MOMb[bh*32+ci], de = DECb[bh*32+ci];
    mval = mo*mval + s;
    u = (1.0f-de)*u + mval;
    GG[off]=u;
  }
}

// ---------------- retrieval: mem_forward with shifted weights, gated ----------------
__global__ __launch_bounds__(512) void k_retr(const float* __restrict__ Qb, const float* __restrict__ G1,
   const float* __restrict__ G2T, const float* __restrict__ GG, const float* __restrict__ mw1,
   const float* __restrict__ mw2, const float* __restrict__ mgamma,
   const float* __restrict__ GATEb, float* __restrict__ OUTT){
  int inst = blockIdx.x;
  int ci = inst & 31, h = (inst>>5)&3, b = inst>>7;
  size_t tok0 = (size_t)b*NN_ + (size_t)ci*64;
  int tid = threadIdx.x;
  __shared__ float qs[64][129];
  __shared__ float wbuf[4224];
  __shared__ float as_[64][33];
  __shared__ float red[64][17];
  __shared__ float rr[64];
  #define W1S(d,j) wbuf[(d)*33+(j)]
  #define W2S(j,d) wbuf[(j)*130+(d)]
  for (int idx=tid; idx<8192; idx+=512){
    int t = idx>>7, d = idx&127;
    qs[t][d] = Qb[(tok0+t)*512 + h*128 + d];
  }
  __syncthreads();
  int tg=tid>>4, dq=tid&15; int t0=tg*2, d0=dq*8;
  float h2a[2][8]={};
  const int first = (ci==0);
  const float* w1p = G1 + (size_t)(inst-1)*65536;
  const float* w2p = G2T + (size_t)(inst-1)*65536;
  for (int jt=0;jt<16;jt++){
    int j0=jt*32;
    if (first){
      for (int idx=tid; idx<4096; idx+=512){
        int d=idx>>5, jj=idx&31;
        W1S(d,jj)=mw1[(size_t)h*65536 + (size_t)d*512 + (j0+jj)];
      }
    } else {
      for (int idx=tid; idx<4096; idx+=512){
        int d=idx>>5, jj=idx&31;
        W1S(d,jj)=w1p[(size_t)d*512 + (j0+jj)];
      }
    }
    __syncthreads();
    {
      int jj0=dq*2;
      float a00=0,a01=0,a10=0,a11=0;
      for (int d=0;d<128;d++){
        float x0=qs[t0][d], x1=qs[t0+1][d];
        float w0=W1S(d,jj0), w1v=W1S(d,jj0+1);
        a00+=x0*w0; a01+=x0*w1v; a10+=x1*w0; a11+=x1*w1v;
      }
      as_[t0][jj0]=geluf(a00);   as_[t0][jj0+1]=geluf(a01);
      as_[t0+1][jj0]=geluf(a10); as_[t0+1][jj0+1]=geluf(a11);
    }
    __syncthreads();
    if (first){
      for (int idx=tid; idx<4096; idx+=512){
        int jj=idx>>7, d=idx&127;
        W2S(jj,d)=mw2[(size_t)h*65536 + (size_t)(j0+jj)*128 + d];
      }
    } else {
      for (int idx=tid; idx<4096; idx+=512){
        int d=idx>>5, jj=idx&31;
        W2S(jj,d)=w2p[(size_t)d*512 + (j0+jj)];
      }
    }
    __syncthreads();
    for (int jj=0;jj<32;jj++){
      float a0=as_[t0][jj], a1=as_[t0+1][jj];
      #pragma unroll
      for (int j2=0;j2<8;j2++){
        float wv=W2S(jj,d0+j2);
        h2a[0][j2]+=a0*wv; h2a[1][j2]+=a1*wv;
      }
    }
    __syncthreads();
  }
  float ss0=0, ss1=0;
  #pragma unroll
  for (int j=0;j<8;j++){ ss0+=h2a[0][j]*h2a[0][j]; ss1+=h2a[1][j]*h2a[1][j]; }
  red[t0][dq]=ss0; red[t0+1][dq]=ss1;
  __syncthreads();
  if (tid<64){
    float s=0;
    #pragma unroll
    for (int q=0;q<16;q++) s+=red[tid][q];
    rr[tid]=rsqrtf(s*(1.0f/128.0f)+1e-6f);
  }
  __syncthreads();
  for (int i=0;i<2;i++){
    int t=t0+i; float r=rr[t];
    float gate = GATEb[(tok0+t)*4+h];
    #pragma unroll
    for (int j=0;j<8;j++){
      int d=d0+j;
      float gv = first? mgamma[h*128+d] : GG[(size_t)(inst-1)*128+d];
      OUTT[(tok0+t)*512 + h*128 + d] = (h2a[i][j]*r*gv + qs[t][d])*gate;
    }
  }
  #undef W1S
  #undef W2S
}

extern "C" void kernel_launch(void* const* d_in, const int* in_sizes, int n_in,
                              void* d_out, int out_size, void* d_ws, size_t ws_size,
                              hipStream_t stream) {
  (void)in_sizes; (void)n_in; (void)out_size; (void)ws_size;
  const float* seq   = (const float*)d_in[0];
  const float* sg    = (const float*)d_in[1];
  const float* rg    = (const float*)d_in[2];
  const float* Wq    = (const float*)d_in[3];
  const float* Wk    = (const float*)d_in[4];
  const float* Wv    = (const float*)d_in[5];
  const float* Wlr   = (const float*)d_in[6];
  const float* blr   = (const float*)d_in[7];
  const float* Wm    = (const float*)d_in[8];
  const float* bm    = (const float*)d_in[9];
  const float* Wd    = (const float*)d_in[10];
  const float* bd    = (const float*)d_in[11];
  const float* Wgate = (const float*)d_in[12];
  const float* Wc    = (const float*)d_in[13];
  const float* mw1   = (const float*)d_in[14];
  const float* mw2   = (const float*)d_in[15];
  const float* mgam  = (const float*)d_in[16];

  float* W = (float*)d_ws;
  float* S    = W + 0;
  float* SR   = W + 2097152;
  float* Kb   = W + 4194304;
  float* Vb   = W + 6291456;
  float* H1B  = W + 8388608;
  float* DH2  = W + 16777216;
  float* Qb   = W + 18874368;
  float* LRb  = W + 20971520;
  float* GATEb= W + 20987904;
  float* MOMb = W + 21004288;
  float* DECb = W + 21004544;
  float* GGb  = W + 21004800;
  float* G1   = W + 21037568;
  float* G2T  = W + 37814784;
  // NS overlays (S,SR dead; Kb,Vb dead after k_dw1):
  unsigned short* ABh = (unsigned short*)(W + 0);        // 512*16384 bf16 = 16 MB over S+SR
  unsigned short* ABl = (unsigned short*)(W + 4194304);  // 16 MB over Kb+Vb
  float* OUTT = W + 8388608;  // overlay H1B slot (free by retrieval time)

  k_rmsnorm<<<4096,256,0,stream>>>(seq, sg, rg, S, SR);
  dim3 gg(64,8);
  k_gemm<<<gg,256,0,stream>>>(S,  Wk, Kb);
  k_gemm<<<gg,256,0,stream>>>(S,  Wv, Vb);
  k_gemm<<<gg,256,0,stream>>>(SR, Wq, Qb);
  k_small<<<64,256,0,stream>>>(S, SR, Wlr, blr, Wm, bm, Wd, bd, Wgate, LRb, GATEb, MOMb, DECb);
  k_fwd<<<256,512,0,stream>>>(Kb, Vb, LRb, mw1, mw2, mgam, H1B, DH2, GGb);
  k_dw2<<<2048,256,0,stream>>>(H1B, DH2, G2T);
  k_dw1<<<4096,256,0,stream>>>(Kb, DH2, H1B, mw2, G1);
  k_ns_prep<<<512,512,0,stream>>>(G1, G2T);
  for (int it=0; it<5; it++){
    k_nsA<<<512,256,0,stream>>>(G1, G2T, ABh, ABl);
    k_nsB<<<512,256,0,stream>>>(ABh, ABl);
    k_nsZ<<<2048,256,0,stream>>>(G1, G2T, ABh, ABl);
  }
  k_scan_mat<<<2048,256,0,stream>>>(G1,  mw1, MOMb, DECb, 0);
  k_scan_mat<<<2048,256,0,stream>>>(G2T, mw2, MOMb, DECb, 1);
  k_scan_gamma<<<8,128,0,stream>>>(GGb, mgam, MOMb, DECb);
  k_retr<<<256,512,0,stream>>>(Qb, G1, G2T, GGb, mw1, mw2, mgam, GATEb, OUTT);
  k_gemm<<<gg,256,0,stream>>>(OUTT, Wc, (float*)d_out);
}

// Round 5
// 1604.349 us; speedup vs baseline: 2.5668x; 1.1324x over previous
//
#include <hip/hip_runtime.h>
#include <hip/hip_bf16.h>
#include <math.h>

#define NN_ 2048

typedef short v8s __attribute__((ext_vector_type(8)));
typedef float v4f __attribute__((ext_vector_type(4)));

__device__ __forceinline__ float geluf(float x){ return 0.5f*x*(1.0f+erff(x*0.70710678118654752440f)); }
__device__ __forceinline__ float gelupf(float x){
  float cdf = 0.5f*(1.0f+erff(x*0.70710678118654752440f));
  float pdf = 0.39894228040143267794f*expf(-0.5f*x*x);
  return cdf + x*pdf;
}
__device__ __forceinline__ float sigm(float x){ return 1.0f/(1.0f+expf(-x)); }

__device__ __forceinline__ unsigned short f2bs(float f){
  __hip_bfloat16 h = __float2bfloat16(f);
  return __builtin_bit_cast(unsigned short, h);
}
__device__ __forceinline__ float bs2f(unsigned short u){
  unsigned v = ((unsigned)u)<<16;
  return __builtin_bit_cast(float, v);
}
__device__ __forceinline__ void hilo(float v, unsigned short &h, unsigned short &l){
  h = f2bs(v); l = f2bs(v - bs2f(h));
}
// XOR-swizzled index into a 128-wide bf16 LDS tile (16B blocks xor'd by row)
__device__ __forceinline__ int swz(int r, int k){
  return r*128 + ((((k>>3) ^ (r&15)) & 15)<<3) + (k&7);
}
// 64-wide variant
__device__ __forceinline__ int swz64(int r, int k){
  return r*64 + ((((k>>3) ^ (r&7)) & 7)<<3) + (k&7);
}

// ---------------- rmsnorm of seq with store/retrieve gains ----------------
__global__ __launch_bounds__(256) void k_rmsnorm(const float* __restrict__ seq, const float* __restrict__ gs,
                          const float* __restrict__ gr, float* __restrict__ S, float* __restrict__ SR){
  int tok = blockIdx.x;
  const float* row = seq + (size_t)tok*512;
  int tid = threadIdx.x;
  float x0 = row[tid];
  float x1 = row[tid+256];
  float ss = x0*x0 + x1*x1;
  #pragma unroll
  for (int o=32;o>0;o>>=1) ss += __shfl_down(ss, o, 64);
  __shared__ float wsum[4];
  int wid = tid>>6, lid = tid&63;
  if (lid==0) wsum[wid]=ss;
  __syncthreads();
  float tot = wsum[0]+wsum[1]+wsum[2]+wsum[3];
  float r = rsqrtf(tot*(1.0f/512.0f) + 1e-6f);
  size_t o0 = (size_t)tok*512 + tid;
  S[o0]      = x0*r*gs[tid];
  S[o0+256]  = x1*r*gs[tid+256];
  SR[o0]     = x0*r*gr[tid];
  SR[o0+256] = x1*r*gr[tid+256];
}

// ---------------- MFMA GEMM: O[4096x512] = X[4096x512] @ Wt[512x512], hi/lo (~fp32) ----------------
__global__ __launch_bounds__(256) void k_gemm_mfma(const float* __restrict__ X, const float* __restrict__ Wt,
                                                   float* __restrict__ O){
  int m0 = blockIdx.x*128, n0 = blockIdx.y*128;
  __shared__ unsigned short Xh[8192], Xl[8192], Wh[8192], Wl[8192];
  int tid = threadIdx.x, w = tid>>6, lane = tid&63, n_l = lane&15, quad = lane>>4;
  v4f acc[2][8];
  #pragma unroll
  for (int i=0;i<2;i++)
    #pragma unroll
    for (int j=0;j<8;j++){ v4f z={0.f,0.f,0.f,0.f}; acc[i][j]=z; }
  for (int kc=0; kc<8; kc++){
    int k0 = kc*64;
    __syncthreads();
    // stage X tile [128 m][64 k] hi/lo
    for (int it=0; it<8; it++){
      int idx = it*1024 + tid*4;
      int r = idx>>6, k = idx&63;
      float4 v = *(const float4*)(X + (size_t)(m0+r)*512 + k0 + k);
      unsigned short h0,h1,h2,h3,l0,l1,l2,l3;
      hilo(v.x,h0,l0); hilo(v.y,h1,l1); hilo(v.z,h2,l2); hilo(v.w,h3,l3);
      int p = swz64(r,k);
      *(unsigned*)&Xh[p]   = (unsigned)h0|((unsigned)h1<<16);
      *(unsigned*)&Xh[p+2] = (unsigned)h2|((unsigned)h3<<16);
      *(unsigned*)&Xl[p]   = (unsigned)l0|((unsigned)l1<<16);
      *(unsigned*)&Xl[p+2] = (unsigned)l2|((unsigned)l3<<16);
    }
    // stage W tile transposed: [128 n][64 k] from Wt[k][n]
    for (int it=0; it<8; it++){
      int idx = it*1024 + tid*4;
      int k = idx>>7, n = idx&127;
      float4 v = *(const float4*)(Wt + (size_t)(k0+k)*512 + n0 + n);
      unsigned short hh,ll;
      hilo(v.x,hh,ll); Wh[swz64(n+0,k)]=hh; Wl[swz64(n+0,k)]=ll;
      hilo(v.y,hh,ll); Wh[swz64(n+1,k)]=hh; Wl[swz64(n+1,k)]=ll;
      hilo(v.z,hh,ll); Wh[swz64(n+2,k)]=hh; Wl[swz64(n+2,k)]=ll;
      hilo(v.w,hh,ll); Wh[swz64(n+3,k)]=hh; Wl[swz64(n+3,k)]=ll;
    }
    __syncthreads();
    #pragma unroll
    for (int ks=0; ks<2; ks++){
      int kf = ks*32 + quad*8;
      v8s ah[2], al[2];
      #pragma unroll
      for (int i=0;i<2;i++){ int r = 32*w + i*16 + n_l; ah[i]=*(const v8s*)&Xh[swz64(r,kf)]; al[i]=*(const v8s*)&Xl[swz64(r,kf)]; }
      #pragma unroll
      for (int nt=0; nt<8; nt++){
        int rn = nt*16 + n_l;
        v8s bh = *(const v8s*)&Wh[swz64(rn,kf)];
        v8s bl = *(const v8s*)&Wl[swz64(rn,kf)];
        #pragma unroll
        for (int i=0;i<2;i++){
          acc[i][nt] = __builtin_amdgcn_mfma_f32_16x16x32_bf16(ah[i], bh, acc[i][nt], 0,0,0);
          acc[i][nt] = __builtin_amdgcn_mfma_f32_16x16x32_bf16(ah[i], bl, acc[i][nt], 0,0,0);
          acc[i][nt] = __builtin_amdgcn_mfma_f32_16x16x32_bf16(al[i], bh, acc[i][nt], 0,0,0);
        }
      }
    }
  }
  #pragma unroll
  for (int i=0;i<2;i++)
    #pragma unroll
    for (int nt=0; nt<8; nt++)
      #pragma unroll
      for (int r=0;r<4;r++)
        O[(size_t)(m0 + 32*w + i*16 + quad*4 + r)*512 + n0 + nt*16 + n_l] = acc[i][nt][r];
}

// ---------------- lr/gate per token, pooled->mom/dec per chunk ----------------
__global__ __launch_bounds__(256) void k_small(const float* __restrict__ S, const float* __restrict__ SR,
    const float* __restrict__ Wlr, const float* __restrict__ blr, const float* __restrict__ Wm,
    const float* __restrict__ bm, const float* __restrict__ Wd, const float* __restrict__ bd,
    const float* __restrict__ Wgate,
    float* __restrict__ LRb, float* __restrict__ GATEb, float* __restrict__ MOMb, float* __restrict__ DECb){
  int bc = blockIdx.x;            // b*32 + ci
  int b = bc>>5, ci = bc&31;
  int tid = threadIdx.x;
  int t = tid>>2, h = tid&3;
  size_t tokbase = (size_t)b*NN_ + (size_t)ci*64;
  __shared__ float pool[512];
  for (int c=tid; c<512; c+=256){
    float s=0;
    for (int t2=0;t2<64;t2++) s += S[(tokbase+t2)*512 + c];
    pool[c] = s*(1.0f/64.0f);
  }
  size_t tok = tokbase + t;
  const float* srow = S + tok*512;
  const float* srrow = SR + tok*512;
  float accl=0, accg=0;
  for (int d=0; d<512; d++){
    accl += srow[d]*Wlr[d*4+h];
    accg += srrow[d]*Wgate[d*4+h];
  }
  accl += blr[h];
  LRb[tok*4+h] = sigm(accl);
  GATEb[tok*4+h] = sigm(accg);
  __syncthreads();
  if (tid<8){
    int hh = tid&3, which = tid>>2;
    float a=0;
    const float* Wx = which? Wd : Wm;
    for (int d=0; d<512; d++) a += pool[d]*Wx[d*4+hh];
    a += which? bd[hh] : bm[hh];
    float v = sigm(a);
    size_t o = ((size_t)b*4+hh)*32 + ci;
    if (which) DECb[o]=v; else MOMb[o]=v;
  }
}

// ---------------- fused memory-MLP forward + rmsnorm backward (MFMA) ----------------
__global__ __launch_bounds__(256) void k_fwd(const float* __restrict__ Kb, const float* __restrict__ Vb,
    const float* __restrict__ LRb, const float* __restrict__ mw1, const float* __restrict__ mw2,
    const float* __restrict__ mgamma, float* __restrict__ H1B, float* __restrict__ DH2,
    float* __restrict__ GG){
  int inst = blockIdx.x;
  int ci = inst & 31, h = (inst>>5)&3, b = inst>>7;
  size_t tok0 = (size_t)b*NN_ + (size_t)ci*64;
  int tid = threadIdx.x, w = tid>>6, lane = tid&63, n_l = lane&15, quad = lane>>4;
  __shared__ unsigned short xh[8192];              // [64 t][128 d] swz, hi only
  __shared__ unsigned short wbh[8192], wbl[8192];  // weight tile
  __shared__ unsigned short ash[4096], asl[4096];  // gelu(h1) tile [64 t][64 j] swz64
  const float* w1 = mw1 + (size_t)h*65536;  // [128 d][512 j]
  const float* w2 = mw2 + (size_t)h*65536;  // [512 j][128 d]
  // stage x (hi only)
  for (int it=0; it<8; it++){
    int idx = it*1024 + tid*4;
    int r = idx>>7, d = idx&127;
    float4 v = *(const float4*)(Kb + (tok0+r)*512 + h*128 + d);
    int p = swz(r,d);
    *(unsigned*)&xh[p]   = (unsigned)f2bs(v.x)|((unsigned)f2bs(v.y)<<16);
    *(unsigned*)&xh[p+2] = (unsigned)f2bs(v.z)|((unsigned)f2bs(v.w)<<16);
  }
  v4f acc2[8];
  #pragma unroll
  for (int j=0;j<8;j++){ v4f z={0.f,0.f,0.f,0.f}; acc2[j]=z; }
  for (int jt=0; jt<8; jt++){
    int j0 = jt*64;
    __syncthreads();
    // stage w1 tile transposed: [64 j][128 d] from w1[d][j]
    for (int it=0; it<8; it++){
      int idx = it*1024 + tid*4;
      int d = idx>>6, jj = idx&63;
      float4 v = *(const float4*)(w1 + (size_t)d*512 + j0 + jj);
      unsigned short hh,ll;
      hilo(v.x,hh,ll); wbh[swz(jj+0,d)]=hh; wbl[swz(jj+0,d)]=ll;
      hilo(v.y,hh,ll); wbh[swz(jj+1,d)]=hh; wbl[swz(jj+1,d)]=ll;
      hilo(v.z,hh,ll); wbh[swz(jj+2,d)]=hh; wbl[swz(jj+2,d)]=ll;
      hilo(v.w,hh,ll); wbh[swz(jj+3,d)]=hh; wbl[swz(jj+3,d)]=ll;
    }
    __syncthreads();
    // phase1: h1 tile (M=64 t, N=64 j, K=128 d)
    v4f acc1[4];
    #pragma unroll
    for (int nt=0; nt<4; nt++){ v4f z={0.f,0.f,0.f,0.f}; acc1[nt]=z; }
    #pragma unroll
    for (int ks=0; ks<4; ks++){
      int kf = ks*32 + quad*8;
      v8s av = *(const v8s*)&xh[swz(16*w + n_l, kf)];
      #pragma unroll
      for (int nt=0; nt<4; nt++){
        v8s bh = *(const v8s*)&wbh[swz(nt*16+n_l, kf)];
        v8s bl = *(const v8s*)&wbl[swz(nt*16+n_l, kf)];
        acc1[nt] = __builtin_amdgcn_mfma_f32_16x16x32_bf16(av, bh, acc1[nt], 0,0,0);
        acc1[nt] = __builtin_amdgcn_mfma_f32_16x16x32_bf16(av, bl, acc1[nt], 0,0,0);
      }
    }
    // epilogue: H1B + gelu -> aS
    #pragma unroll
    for (int nt=0; nt<4; nt++)
      #pragma unroll
      for (int r=0;r<4;r++){
        int t = 16*w + quad*4 + r;
        int jj = nt*16 + n_l;
        float hv = acc1[nt][r];
        H1B[(size_t)inst*32768 + (size_t)t*512 + j0 + jj] = hv;
        float g = geluf(hv);
        unsigned short gh = f2bs(g);
        ash[swz64(t, jj)] = gh;
        asl[swz64(t, jj)] = f2bs(g - bs2f(gh));
      }
    __syncthreads();
    // stage w2 tile transposed: [128 d][64 j] from w2[j][d]
    for (int it=0; it<8; it++){
      int idx = it*1024 + tid*4;
      int jj = idx>>7, d = idx&127;
      float4 v = *(const float4*)(w2 + (size_t)(j0+jj)*128 + d);
      unsigned short hh,ll;
      hilo(v.x,hh,ll); wbh[swz64(d+0,jj)]=hh; wbl[swz64(d+0,jj)]=ll;
      hilo(v.y,hh,ll); wbh[swz64(d+1,jj)]=hh; wbl[swz64(d+1,jj)]=ll;
      hilo(v.z,hh,ll); wbh[swz64(d+2,jj)]=hh; wbl[swz64(d+2,jj)]=ll;
      hilo(v.w,hh,ll); wbh[swz64(d+3,jj)]=hh; wbl[swz64(d+3,jj)]=ll;
    }
    __syncthreads();
    // phase2: h2 += a @ w2 (M=64 t, N=128 d, K=64 j)
    #pragma unroll
    for (int ks=0; ks<2; ks++){
      int kf = ks*32 + quad*8;
      v8s ah = *(const v8s*)&ash[swz64(16*w + n_l, kf)];
      v8s al = *(const v8s*)&asl[swz64(16*w + n_l, kf)];
      #pragma unroll
      for (int nt=0; nt<8; nt++){
        v8s bh = *(const v8s*)&wbh[swz64(nt*16+n_l, kf)];
        v8s bl = *(const v8s*)&wbl[swz64(nt*16+n_l, kf)];
        acc2[nt] = __builtin_amdgcn_mfma_f32_16x16x32_bf16(ah, bh, acc2[nt], 0,0,0);
        acc2[nt] = __builtin_amdgcn_mfma_f32_16x16x32_bf16(ah, bl, acc2[nt], 0,0,0);
        acc2[nt] = __builtin_amdgcn_mfma_f32_16x16x32_bf16(al, bh, acc2[nt], 0,0,0);
      }
    }
  }
  // phase3: rmsnorm backward on h2 (C-layout: row t = 16w+quad*4+r, col d = nt*16+n_l)
  float* sgg = (float*)wbh;
  __syncthreads();
  if (tid<128) sgg[tid]=0.0f;
  __syncthreads();
  float ss[4] = {0,0,0,0};
  #pragma unroll
  for (int nt=0; nt<8; nt++)
    #pragma unroll
    for (int r=0;r<4;r++) ss[r] += acc2[nt][r]*acc2[nt][r];
  #pragma unroll
  for (int m=1;m<16;m<<=1)
    #pragma unroll
    for (int r=0;r<4;r++) ss[r] += __shfl_xor(ss[r], m, 64);
  float rr[4];
  #pragma unroll
  for (int r=0;r<4;r++) rr[r] = rsqrtf(ss[r]*(1.0f/128.0f) + 1e-6f);
  float gv[8];
  #pragma unroll
  for (int nt=0; nt<8; nt++) gv[nt] = mgamma[h*128 + nt*16 + n_l];
  float lrv[4];
  #pragma unroll
  for (int r=0;r<4;r++) lrv[r] = LRb[(tok0 + 16*w + quad*4 + r)*4 + h]*(2.0f/128.0f);
  float dnv[8][4]; float dot[4]={0,0,0,0}; float ggp[8];
  #pragma unroll
  for (int nt=0; nt<8; nt++) ggp[nt]=0.0f;
  #pragma unroll
  for (int nt=0; nt<8; nt++)
    #pragma unroll
    for (int r=0;r<4;r++){
      int t = 16*w + quad*4 + r;
      int d = nt*16 + n_l;
      float xv = Kb[(tok0+t)*512 + h*128 + d];
      float vv = Vb[(tok0+t)*512 + h*128 + d];
      float nval = acc2[nt][r]*rr[r];
      float pred = nval*gv[nt] + xv;
      float dp = lrv[r]*(pred - vv);
      ggp[nt] += dp*nval;
      float dn = dp*gv[nt];
      dnv[nt][r] = dn;
      dot[r] += dn*acc2[nt][r];
    }
  #pragma unroll
  for (int nt=0; nt<8; nt++) atomicAdd(&sgg[nt*16+n_l], ggp[nt]);
  #pragma unroll
  for (int m=1;m<16;m<<=1)
    #pragma unroll
    for (int r=0;r<4;r++) dot[r] += __shfl_xor(dot[r], m, 64);
  #pragma unroll
  for (int nt=0; nt<8; nt++)
    #pragma unroll
    for (int r=0;r<4;r++){
      int t = 16*w + quad*4 + r;
      int d = nt*16 + n_l;
      float dt = dot[r]*rr[r]*rr[r]*rr[r]*(1.0f/128.0f);
      DH2[(size_t)inst*8192 + (size_t)t*128 + d] = rr[r]*dnv[nt][r] - dt*acc2[nt][r];
    }
  __syncthreads();
  if (tid<128) GG[(size_t)inst*128+tid] = -sgg[tid];
}

// ---------------- G2T[d][j] = -sum_t gelu(h1[t,j]) * dh2[t,d]  ----------------
__global__ __launch_bounds__(256) void k_dw2(const float* __restrict__ H1B, const float* __restrict__ DH2,
                      float* __restrict__ G2T){
  int inst = blockIdx.x>>3;
  int jt = blockIdx.x&7; int j0 = jt*64;
  int tid = threadIdx.x;
  __shared__ float dh2s[64][129];
  __shared__ float as2[64][65];
  for (int idx=tid; idx<8192; idx+=256){ int t=idx>>7, d=idx&127; dh2s[t][d]=DH2[(size_t)inst*8192+idx]; }
  for (int idx=tid; idx<4096; idx+=256){ int t=idx>>6, jj=idx&63; as2[t][jj]=geluf(H1B[(size_t)inst*32768+(size_t)t*512+j0+jj]); }
  __syncthreads();
  int dg=tid>>3, jg=tid&7; int d0=dg*4, jj0=jg*8;
  float acc[4][8]={};
  for (int t=0;t<64;t++){
    float dv[4], av[8];
    #pragma unroll
    for (int i=0;i<4;i++) dv[i]=dh2s[t][d0+i];
    #pragma unroll
    for (int j=0;j<8;j++) av[j]=as2[t][jj0+j];
    #pragma unroll
    for (int i=0;i<4;i++)
      #pragma unroll
      for (int j=0;j<8;j++) acc[i][j]+=av[j]*dv[i];
  }
  for (int i=0;i<4;i++)
    #pragma unroll
    for (int j=0;j<8;j++)
      G2T[(size_t)inst*65536 + (size_t)(d0+i)*512 + j0+jj0+j] = -acc[i][j];
}

// ---------------- da = dh2 @ w2^T ; dh1 = da*gelu'(h1); G1 = -x^T @ dh1 ----------------
__global__ __launch_bounds__(256) void k_dw1(const float* __restrict__ Kb, const float* __restrict__ DH2,
    const float* __restrict__ H1B, const float* __restrict__ mw2, float* __restrict__ G1){
  int inst = blockIdx.x>>4; int jt = blockIdx.x&15; int j0=jt*32;
  int ci = inst&31, h=(inst>>5)&3, b=inst>>7;
  size_t tok0 = (size_t)b*NN_ + (size_t)ci*64;
  int tid=threadIdx.x;
  __shared__ float buf[64][129];
  __shared__ float w2s[32][130];
  __shared__ float dh1s[64][33];
  for (int idx=tid; idx<8192; idx+=256){ int t=idx>>7, d=idx&127; buf[t][d]=DH2[(size_t)inst*8192+idx]; }
  for (int idx=tid; idx<4096; idx+=256){ int jj=idx>>7, d=idx&127; w2s[jj][d]=mw2[(size_t)h*65536+(size_t)(j0+jj)*128+d]; }
  __syncthreads();
  int tg=tid>>3, jg=tid&7; int t0=tg*2, jj0=jg*4;
  float da[2][4]={};
  for (int d=0; d<128; d++){
    float q0=buf[t0][d], q1=buf[t0+1][d];
    #pragma unroll
    for (int j=0;j<4;j++){ float wv=w2s[jj0+j][d]; da[0][j]+=q0*wv; da[1][j]+=q1*wv; }
  }
  float dh1v[2][4];
  for (int i=0;i<2;i++)
    for (int j=0;j<4;j++){
      float hv = H1B[(size_t)inst*32768 + (size_t)(t0+i)*512 + j0+jj0+j];
      dh1v[i][j] = da[i][j]*gelupf(hv);
    }
  __syncthreads();
  for (int i=0;i<2;i++)
    for (int j=0;j<4;j++) dh1s[t0+i][jj0+j]=dh1v[i][j];
  for (int idx=tid; idx<8192; idx+=256){ int t=idx>>7, d=idx&127; buf[t][d]=Kb[(tok0+t)*512 + h*128 + d]; }
  __syncthreads();
  int dg=tid>>3; int d0=dg*4;
  float acc[4][4]={};
  for (int t=0;t<64;t++){
    float xv[4], hv[4];
    #pragma unroll
    for (int i=0;i<4;i++) xv[i]=buf[t][d0+i];
    #pragma unroll
    for (int j=0;j<4;j++) hv[j]=dh1s[t][jj0+j];
    #pragma unroll
    for (int i=0;i<4;i++)
      #pragma unroll
      for (int j=0;j<4;j++) acc[i][j]+=xv[i]*hv[j];
  }
  for (int i=0;i<4;i++)
    for (int j=0;j<4;j++)
      G1[(size_t)inst*65536 + (size_t)(d0+i)*512 + j0+jj0+j] = -acc[i][j];
}

// ---------------- NS prep: Frobenius-normalize each 128x512 matrix in place (fp32) ----------------
__global__ __launch_bounds__(512) void k_ns_prep(float* __restrict__ G1, float* __restrict__ G2T){
  int m = blockIdx.x;
  float* t = (m<256)? (G1 + (size_t)m*65536) : (G2T + (size_t)(m-256)*65536);
  int tid=threadIdx.x;
  float ss=0;
  for (int idx=tid; idx<65536; idx+=512){ float v=t[idx]; ss+=v*v; }
  #pragma unroll
  for (int o=32;o>0;o>>=1) ss += __shfl_down(ss, o, 64);
  __shared__ float wsum[8];
  int wid=tid>>6, lid=tid&63;
  if (lid==0) wsum[wid]=ss;
  __syncthreads();
  float tot=0;
  #pragma unroll
  for (int w=0;w<8;w++) tot+=wsum[w];
  float scale = 1.0f/fmaxf(sqrtf(tot), 1e-7f);
  for (int idx=tid; idx<65536; idx+=512) t[idx]*=scale;
}

// ---------------- NS step 1: A = t@t^T, split -> ABh/ABl (bf16 planes) ----------------
__global__ __launch_bounds__(256) void k_nsA(const float* __restrict__ G1, const float* __restrict__ G2T,
                                             unsigned short* __restrict__ ABh, unsigned short* __restrict__ ABl){
  int m = blockIdx.x;
  const float* t = (m<256)? (G1 + (size_t)m*65536) : (G2T + (size_t)(m-256)*65536);
  __shared__ unsigned short th[16384];
  __shared__ unsigned short tl[16384];
  int tid = threadIdx.x;
  int w = tid>>6, lane = tid&63;
  int n = lane&15, quad = lane>>4;
  v4f acc[2][8];
  #pragma unroll
  for (int i=0;i<2;i++)
    #pragma unroll
    for (int j=0;j<8;j++){ v4f z = {0.f,0.f,0.f,0.f}; acc[i][j]=z; }
  for (int c=0;c<4;c++){
    int k0 = c*128;
    for (int it=0; it<16; it++){
      int idx = it*1024 + tid*4;
      int r = idx>>7, k = idx&127;
      float4 v = *(const float4*)(t + (size_t)r*512 + k0 + k);
      union { unsigned long long q; unsigned short s[4]; } uh, ulw;
      uh.s[0]=f2bs(v.x); uh.s[1]=f2bs(v.y); uh.s[2]=f2bs(v.z); uh.s[3]=f2bs(v.w);
      ulw.s[0]=f2bs(v.x-bs2f(uh.s[0])); ulw.s[1]=f2bs(v.y-bs2f(uh.s[1]));
      ulw.s[2]=f2bs(v.z-bs2f(uh.s[2])); ulw.s[3]=f2bs(v.w-bs2f(uh.s[3]));
      *(unsigned long long*)&th[swz(r,k)] = uh.q;
      *(unsigned long long*)&tl[swz(r,k)] = ulw.q;
    }
    __syncthreads();
    for (int kk=0; kk<128; kk+=32){
      int kf = kk + quad*8;
      v8s ah[2], al[2], bh[8], bl[8];
      #pragma unroll
      for (int i=0;i<2;i++){ int r = w*32 + i*16 + n; ah[i]=*(const v8s*)&th[swz(r,kf)]; al[i]=*(const v8s*)&tl[swz(r,kf)]; }
      #pragma unroll
      for (int j=0;j<8;j++){ int r = j*16 + n; bh[j]=*(const v8s*)&th[swz(r,kf)]; bl[j]=*(const v8s*)&tl[swz(r,kf)]; }
      #pragma unroll
      for (int i=0;i<2;i++)
        #pragma unroll
        for (int j=0;j<8;j++){
          acc[i][j] = __builtin_amdgcn_mfma_f32_16x16x32_bf16(ah[i], bh[j], acc[i][j], 0,0,0);
          acc[i][j] = __builtin_amdgcn_mfma_f32_16x16x32_bf16(ah[i], bl[j], acc[i][j], 0,0,0);
          acc[i][j] = __builtin_amdgcn_mfma_f32_16x16x32_bf16(al[i], bh[j], acc[i][j], 0,0,0);
        }
    }
    __syncthreads();
  }
  #pragma unroll
  for (int i=0;i<2;i++)
    #pragma unroll
    for (int j=0;j<8;j++)
      #pragma unroll
      for (int r=0;r<4;r++){
        int row = w*32 + i*16 + quad*4 + r;
        int col = j*16 + n;
        float v = acc[i][j][r];
        unsigned short hs = f2bs(v);
        th[row*128+col] = hs;
        tl[row*128+col] = f2bs(v - bs2f(hs));
      }
  __syncthreads();
  for (int it=0; it<8; it++){
    int idx = it*2048 + tid*8;
    *(v8s*)&ABh[(size_t)m*16384 + idx] = *(const v8s*)&th[idx];
    *(v8s*)&ABl[(size_t)m*16384 + idx] = *(const v8s*)&tl[idx];
  }
}

// ---------------- NS step 2: B = b*A + c*A@A, split, in-place over AB planes ----------------
__global__ __launch_bounds__(256) void k_nsB(unsigned short* __restrict__ ABh, unsigned short* __restrict__ ABl){
  int m = blockIdx.x;
  __shared__ unsigned short Ah[16384];
  __shared__ unsigned short Al[16384];
  int tid = threadIdx.x;
  int w = tid>>6, lane = tid&63;
  int n = lane&15, quad = lane>>4;
  for (int it=0; it<8; it++){
    int idx = it*2048 + tid*8;
    int r = idx>>7, k = idx&127;
    *(v8s*)&Ah[swz(r,k)] = *(const v8s*)&ABh[(size_t)m*16384 + idx];
    *(v8s*)&Al[swz(r,k)] = *(const v8s*)&ABl[(size_t)m*16384 + idx];
  }
  __syncthreads();
  v4f acc[2][8];
  #pragma unroll
  for (int i=0;i<2;i++)
    #pragma unroll
    for (int j=0;j<8;j++){ v4f z = {0.f,0.f,0.f,0.f}; acc[i][j]=z; }
  for (int kk=0; kk<128; kk+=32){
    int kf = kk + quad*8;
    v8s ah[2], al2[2], bh[8], bl[8];
    #pragma unroll
    for (int i=0;i<2;i++){ int r = w*32 + i*16 + n; ah[i]=*(const v8s*)&Ah[swz(r,kf)]; al2[i]=*(const v8s*)&Al[swz(r,kf)]; }
    #pragma unroll
    for (int j=0;j<8;j++){ int r = j*16 + n; bh[j]=*(const v8s*)&Ah[swz(r,kf)]; bl[j]=*(const v8s*)&Al[swz(r,kf)]; }
    #pragma unroll
    for (int i=0;i<2;i++)
      #pragma unroll
      for (int j=0;j<8;j++){
        acc[i][j] = __builtin_amdgcn_mfma_f32_16x16x32_bf16(ah[i], bh[j], acc[i][j], 0,0,0);
        acc[i][j] = __builtin_amdgcn_mfma_f32_16x16x32_bf16(ah[i], bl[j], acc[i][j], 0,0,0);
        acc[i][j] = __builtin_amdgcn_mfma_f32_16x16x32_bf16(al2[i], bh[j], acc[i][j], 0,0,0);
      }
  }
  const float CB=-4.775f, CC=2.0315f;
  float Bv[2][8][4];
  #pragma unroll
  for (int i=0;i<2;i++)
    #pragma unroll
    for (int j=0;j<8;j++)
      #pragma unroll
      for (int r=0;r<4;r++){
        int row = w*32 + i*16 + quad*4 + r;
        int col = j*16 + n;
        float av = bs2f(Ah[swz(row,col)]) + bs2f(Al[swz(row,col)]);
        Bv[i][j][r] = CB*av + CC*acc[i][j][r];
      }
  __syncthreads();
  #pragma unroll
  for (int i=0;i<2;i++)
    #pragma unroll
    for (int j=0;j<8;j++)
      #pragma unroll
      for (int r=0;r<4;r++){
        int row = w*32 + i*16 + quad*4 + r;
        int col = j*16 + n;
        float v = Bv[i][j][r];
        unsigned short hs = f2bs(v);
        Ah[row*128+col] = hs;
        Al[row*128+col] = f2bs(v - bs2f(hs));
      }
  __syncthreads();
  for (int it=0; it<8; it++){
    int idx = it*2048 + tid*8;
    *(v8s*)&ABh[(size_t)m*16384 + idx] = *(const v8s*)&Ah[idx];
    *(v8s*)&ABl[(size_t)m*16384 + idx] = *(const v8s*)&Al[idx];
  }
}

// ---------------- NS step 3: t' = a*t + B@t per 128-col strip (B symmetric), in place ----------------
__global__ __launch_bounds__(256) void k_nsZ(float* __restrict__ G1, float* __restrict__ G2T,
                                             const unsigned short* __restrict__ ABh, const unsigned short* __restrict__ ABl){
  int blk = blockIdx.x;
  int m = blk>>2, s = blk&3, c0 = s*128;
  float* t = (m<256)? (G1 + (size_t)m*65536) : (G2T + (size_t)(m-256)*65536);
  __shared__ __align__(16) unsigned char smem[65536];
  unsigned short* Bh = (unsigned short*)smem;
  unsigned short* Bl = Bh + 8192;
  unsigned short* uh = Bh + 16384;
  unsigned short* ul = Bh + 24576;
  float* Zs = (float*)smem;
  int tid = threadIdx.x;
  int w = tid>>6, lane = tid&63;
  int n = lane&15, quad = lane>>4;
  v4f acc[2][8];
  #pragma unroll
  for (int i=0;i<2;i++)
    #pragma unroll
    for (int j=0;j<8;j++){ v4f z = {0.f,0.f,0.f,0.f}; acc[i][j]=z; }
  for (int c=0;c<2;c++){
    int k0 = c*64;
    for (int it=0; it<4; it++){
      int idx = it*2048 + tid*8;
      int r = idx>>6, k = idx&63;
      *(v8s*)&Bh[swz64(r,k)] = *(const v8s*)&ABh[(size_t)m*16384 + (size_t)r*128 + k0 + k];
      *(v8s*)&Bl[swz64(r,k)] = *(const v8s*)&ABl[(size_t)m*16384 + (size_t)r*128 + k0 + k];
    }
    for (int it=0; it<8; it++){
      int idx = it*1024 + tid*4;
      int kr = idx>>7, j = idx&127;
      float4 v = *(const float4*)(t + (size_t)(k0+kr)*512 + c0 + j);
      float vv[4] = {v.x, v.y, v.z, v.w};
      #pragma unroll
      for (int e=0;e<4;e++){
        unsigned short hs = f2bs(vv[e]);
        uh[swz64(j+e, kr)] = hs;
        ul[swz64(j+e, kr)] = f2bs(vv[e] - bs2f(hs));
      }
    }
    __syncthreads();
    #pragma unroll
    for (int kk=0; kk<64; kk+=32){
      int kf = kk + quad*8;
      v8s ah[2], al2[2], bhf[8], blf[8];
      #pragma unroll
      for (int i=0;i<2;i++){ int r = w*32 + i*16 + n; ah[i]=*(const v8s*)&Bh[swz64(r,kf)]; al2[i]=*(const v8s*)&Bl[swz64(r,kf)]; }
      #pragma unroll
      for (int j=0;j<8;j++){ int r = j*16 + n; bhf[j]=*(const v8s*)&uh[swz64(r,kf)]; blf[j]=*(const v8s*)&ul[swz64(r,kf)]; }
      #pragma unroll
      for (int i=0;i<2;i++)
        #pragma unroll
        for (int j=0;j<8;j++){
          acc[i][j] = __builtin_amdgcn_mfma_f32_16x16x32_bf16(ah[i], bhf[j], acc[i][j], 0,0,0);
          acc[i][j] = __builtin_amdgcn_mfma_f32_16x16x32_bf16(ah[i], blf[j], acc[i][j], 0,0,0);
          acc[i][j] = __builtin_amdgcn_mfma_f32_16x16x32_bf16(al2[i], bhf[j], acc[i][j], 0,0,0);
        }
    }
    __syncthreads();
  }
  #pragma unroll
  for (int i=0;i<2;i++)
    #pragma unroll
    for (int j=0;j<8;j++)
      #pragma unroll
      for (int r=0;r<4;r++){
        int row = w*32 + i*16 + quad*4 + r;
        int col = j*16 + n;
        Zs[row*128+col] = acc[i][j][r];
      }
  __syncthreads();
  const float CA = 3.4445f;
  for (int it=0; it<16; it++){
    int idx = it*1024 + tid*4;
    int i = idx>>7, j = idx&127;
    float* dst = t + (size_t)i*512 + c0 + j;
    float4 told = *(const float4*)dst;
    float4 o;
    o.x = CA*told.x + Zs[i*128+j+0];
    o.y = CA*told.y + Zs[i*128+j+1];
    o.z = CA*told.z + Zs[i*128+j+2];
    o.w = CA*told.w + Zs[i*128+j+3];
    *(float4*)dst = o;
  }
}

// ---------------- momentum + decay scans (float4/thread, prefetch), per (b,h) strand ----------------
__global__ __launch_bounds__(256) void k_scan_mat(float* __restrict__ G, const float* __restrict__ mw,
    const float* __restrict__ MOMb, const float* __restrict__ DECb, int transposed){
  int bh = blockIdx.x>>6;
  int eblk = blockIdx.x&63;
  int e = (eblk*256 + threadIdx.x)*4;
  int h = bh&3;
  float4 u;
  if (transposed){
    int d = e>>9; int j = e&511;
    u.x = mw[(size_t)h*65536 + (size_t)(j+0)*128 + d];
    u.y = mw[(size_t)h*65536 + (size_t)(j+1)*128 + d];
    u.z = mw[(size_t)h*65536 + (size_t)(j+2)*128 + d];
    u.w = mw[(size_t)h*65536 + (size_t)(j+3)*128 + d];
  } else {
    u = *(const float4*)(mw + (size_t)h*65536 + e);
  }
  float4 mval = {0,0,0,0};
  size_t base = (size_t)(bh*32)*65536 + e;
  float4 s = *(const float4*)(G + base);
  for (int ci=0; ci<32; ci++){
    size_t off = base + (size_t)ci*65536;
    float4 s_next;
    if (ci<31) s_next = *(const float4*)(G + off + 65536);
    float mo = MOMb[bh*32+ci], de = DECb[bh*32+ci];
    float om = 1.0f-de;
    mval.x = mo*mval.x + s.x; mval.y = mo*mval.y + s.y;
    mval.z = mo*mval.z + s.z; mval.w = mo*mval.w + s.w;
    u.x = om*u.x + mval.x; u.y = om*u.y + mval.y;
    u.z = om*u.z + mval.z; u.w = om*u.w + mval.w;
    *(float4*)(G + off) = u;
    s = s_next;
  }
}

__global__ __launch_bounds__(128) void k_scan_gamma(float* __restrict__ GG, const float* __restrict__ mg,
    const float* __restrict__ MOMb, const float* __restrict__ DECb){
  int bh=blockIdx.x; int e=threadIdx.x; int h=bh&3;
  float u = mg[h*128+e]; float mval=0;
  for (int ci=0;ci<32;ci++){
    size_t off = ((size_t)(bh*32+ci))*128 + e;
    float s = GG[off];
    float mo = MOMb[bh*32+ci], de = DECb[bh*32+ci];
    mval = mo*mval + s;
    u = (1.0f-de)*u + mval;
    GG[off]=u;
  }
}

// ---------------- retrieval: mem_forward with shifted weights (MFMA), gated ----------------
__global__ __launch_bounds__(256) void k_retr(const float* __restrict__ Qb, const float* __restrict__ G1,
   const float* __restrict__ G2T, const float* __restrict__ GG, const float* __restrict__ mw1,
   const float* __restrict__ mw2, const float* __restrict__ mgamma,
   const float* __restrict__ GATEb, float* __restrict__ OUTT){
  int inst = blockIdx.x;
  int ci = inst & 31, h = (inst>>5)&3, b = inst>>7;
  size_t tok0 = (size_t)b*NN_ + (size_t)ci*64;
  int tid = threadIdx.x, w = tid>>6, lane = tid&63, n_l = lane&15, quad = lane>>4;
  __shared__ unsigned short xh[8192];
  __shared__ unsigned short wbh[8192], wbl[8192];
  __shared__ unsigned short ash[4096], asl[4096];
  const int first = (ci==0);
  const float* w1 = first ? (mw1 + (size_t)h*65536) : (G1 + (size_t)(inst-1)*65536);   // [128 d][512 j]
  const float* w2j = mw2 + (size_t)h*65536;                                            // [512 j][128 d]
  const float* w2d = G2T + (size_t)(inst-1)*65536;                                     // [128 d][512 j]
  // stage q (hi only)
  for (int it=0; it<8; it++){
    int idx = it*1024 + tid*4;
    int r = idx>>7, d = idx&127;
    float4 v = *(const float4*)(Qb + (tok0+r)*512 + h*128 + d);
    int p = swz(r,d);
    *(unsigned*)&xh[p]   = (unsigned)f2bs(v.x)|((unsigned)f2bs(v.y)<<16);
    *(unsigned*)&xh[p+2] = (unsigned)f2bs(v.z)|((unsigned)f2bs(v.w)<<16);
  }
  v4f acc2[8];
  #pragma unroll
  for (int j=0;j<8;j++){ v4f z={0.f,0.f,0.f,0.f}; acc2[j]=z; }
  for (int jt=0; jt<8; jt++){
    int j0 = jt*64;
    __syncthreads();
    // stage w1 tile transposed: [64 j][128 d] from w1[d][j]
    for (int it=0; it<8; it++){
      int idx = it*1024 + tid*4;
      int d = idx>>6, jj = idx&63;
      float4 v = *(const float4*)(w1 + (size_t)d*512 + j0 + jj);
      unsigned short hh,ll;
      hilo(v.x,hh,ll); wbh[swz(jj+0,d)]=hh; wbl[swz(jj+0,d)]=ll;
      hilo(v.y,hh,ll); wbh[swz(jj+1,d)]=hh; wbl[swz(jj+1,d)]=ll;
      hilo(v.z,hh,ll); wbh[swz(jj+2,d)]=hh; wbl[swz(jj+2,d)]=ll;
      hilo(v.w,hh,ll); wbh[swz(jj+3,d)]=hh; wbl[swz(jj+3,d)]=ll;
    }
    __syncthreads();
    // phase1
    v4f acc1[4];
    #pragma unroll
    for (int nt=0; nt<4; nt++){ v4f z={0.f,0.f,0.f,0.f}; acc1[nt]=z; }
    #pragma unroll
    for (int ks=0; ks<4; ks++){
      int kf = ks*32 + quad*8;
      v8s av = *(const v8s*)&xh[swz(16*w + n_l, kf)];
      #pragma unroll
      for (int nt=0; nt<4; nt++){
        v8s bh = *(const v8s*)&wbh[swz(nt*16+n_l, kf)];
        v8s bl = *(const v8s*)&wbl[swz(nt*16+n_l, kf)];
        acc1[nt] = __builtin_amdgcn_mfma_f32_16x16x32_bf16(av, bh, acc1[nt], 0,0,0);
        acc1[nt] = __builtin_amdgcn_mfma_f32_16x16x32_bf16(av, bl, acc1[nt], 0,0,0);
      }
    }
    #pragma unroll
    for (int nt=0; nt<4; nt++)
      #pragma unroll
      for (int r=0;r<4;r++){
        int t = 16*w + quad*4 + r;
        int jj = nt*16 + n_l;
        float g = geluf(acc1[nt][r]);
        unsigned short gh = f2bs(g);
        ash[swz64(t, jj)] = gh;
        asl[swz64(t, jj)] = f2bs(g - bs2f(gh));
      }
    __syncthreads();
    // stage w2 tile: [128 d][64 j]
    if (first){
      for (int it=0; it<8; it++){
        int idx = it*1024 + tid*4;
        int jj = idx>>7, d = idx&127;
        float4 v = *(const float4*)(w2j + (size_t)(j0+jj)*128 + d);
        unsigned short hh,ll;
        hilo(v.x,hh,ll); wbh[swz64(d+0,jj)]=hh; wbl[swz64(d+0,jj)]=ll;
        hilo(v.y,hh,ll); wbh[swz64(d+1,jj)]=hh; wbl[swz64(d+1,jj)]=ll;
        hilo(v.z,hh,ll); wbh[swz64(d+2,jj)]=hh; wbl[swz64(d+2,jj)]=ll;
        hilo(v.w,hh,ll); wbh[swz64(d+3,jj)]=hh; wbl[swz64(d+3,jj)]=ll;
      }
    } else {
      for (int it=0; it<8; it++){
        int idx = it*1024 + tid*4;
        int d = idx>>6, jj = idx&63;
        float4 v = *(const float4*)(w2d + (size_t)d*512 + j0 + jj);
        unsigned short h0,h1,h2,h3,l0,l1,l2,l3;
        hilo(v.x,h0,l0); hilo(v.y,h1,l1); hilo(v.z,h2,l2); hilo(v.w,h3,l3);
        int p = swz64(d,jj);
        *(unsigned*)&wbh[p]   = (unsigned)h0|((unsigned)h1<<16);
        *(unsigned*)&wbh[p+2] = (unsigned)h2|((unsigned)h3<<16);
        *(unsigned*)&wbl[p]   = (unsigned)l0|((unsigned)l1<<16);
        *(unsigned*)&wbl[p+2] = (unsigned)l2|((unsigned)l3<<16);
      }
    }
    __syncthreads();
    // phase2
    #pragma unroll
    for (int ks=0; ks<2; ks++){
      int kf = ks*32 + quad*8;
      v8s ah = *(const v8s*)&ash[swz64(16*w + n_l, kf)];
      v8s al = *(const v8s*)&asl[swz64(16*w + n_l, kf)];
      #pragma unroll
      for (int nt=0; nt<8; nt++){
        v8s bh = *(const v8s*)&wbh[swz64(nt*16+n_l, kf)];
        v8s bl = *(const v8s*)&wbl[swz64(nt*16+n_l, kf)];
        acc2[nt] = __builtin_amdgcn_mfma_f32_16x16x32_bf16(ah, bh, acc2[nt], 0,0,0);
        acc2[nt] = __builtin_amdgcn_mfma_f32_16x16x32_bf16(ah, bl, acc2[nt], 0,0,0);
        acc2[nt] = __builtin_amdgcn_mfma_f32_16x16x32_bf16(al, bh, acc2[nt], 0,0,0);
      }
    }
  }
  // epilogue: rmsnorm + gamma + residual + gate
  float ss[4] = {0,0,0,0};
  #pragma unroll
  for (int nt=0; nt<8; nt++)
    #pragma unroll
    for (int r=0;r<4;r++) ss[r] += acc2[nt][r]*acc2[nt][r];
  #pragma unroll
  for (int m=1;m<16;m<<=1)
    #pragma unroll
    for (int r=0;r<4;r++) ss[r] += __shfl_xor(ss[r], m, 64);
  float rr[4];
  #pragma unroll
  for (int r=0;r<4;r++) rr[r] = rsqrtf(ss[r]*(1.0f/128.0f) + 1e-6f);
  float gv[8];
  #pragma unroll
  for (int nt=0; nt<8; nt++){
    int d = nt*16 + n_l;
    gv[nt] = first ? mgamma[h*128+d] : GG[(size_t)(inst-1)*128+d];
  }
  float gate[4];
  #pragma unroll
  for (int r=0;r<4;r++) gate[r] = GATEb[(tok0 + 16*w + quad*4 + r)*4 + h];
  #pragma unroll
  for (int nt=0; nt<8; nt++)
    #pragma unroll
    for (int r=0;r<4;r++){
      int t = 16*w + quad*4 + r;
      int d = nt*16 + n_l;
      float qv = Qb[(tok0+t)*512 + h*128 + d];
      OUTT[(tok0+t)*512 + h*128 + d] = (acc2[nt][r]*rr[r]*gv[nt] + qv)*gate[r];
    }
}

extern "C" void kernel_launch(void* const* d_in, const int* in_sizes, int n_in,
                              void* d_out, int out_size, void* d_ws, size_t ws_size,
                              hipStream_t stream) {
  (void)in_sizes; (void)n_in; (void)out_size; (void)ws_size;
  const float* seq   = (const float*)d_in[0];
  const float* sg    = (const float*)d_in[1];
  const float* rg    = (const float*)d_in[2];
  const float* Wq    = (const float*)d_in[3];
  const float* Wk    = (const float*)d_in[4];
  const float* Wv    = (const float*)d_in[5];
  const float* Wlr   = (const float*)d_in[6];
  const float* blr   = (const float*)d_in[7];
  const float* Wm    = (const float*)d_in[8];
  const float* bm    = (const float*)d_in[9];
  const float* Wd    = (const float*)d_in[10];
  const float* bd    = (const float*)d_in[11];
  const float* Wgate = (const float*)d_in[12];
  const float* Wc    = (const float*)d_in[13];
  const float* mw1   = (const float*)d_in[14];
  const float* mw2   = (const float*)d_in[15];
  const float* mgam  = (const float*)d_in[16];

  float* W = (float*)d_ws;
  float* S    = W + 0;
  float* SR   = W + 2097152;
  float* Kb   = W + 4194304;
  float* Vb   = W + 6291456;
  float* H1B  = W + 8388608;
  float* DH2  = W + 16777216;
  float* Qb   = W + 18874368;
  float* LRb  = W + 20971520;
  float* GATEb= W + 20987904;
  float* MOMb = W + 21004288;
  float* DECb = W + 21004544;
  float* GGb  = W + 21004800;
  float* G1   = W + 21037568;
  float* G2T  = W + 37814784;
  unsigned short* ABh = (unsigned short*)(W + 0);        // overlay S+SR (dead by NS time)
  unsigned short* ABl = (unsigned short*)(W + 4194304);  // overlay Kb+Vb (dead after k_dw1)
  float* OUTT = W + 8388608;  // overlay H1B slot (free by retrieval time)

  k_rmsnorm<<<4096,256,0,stream>>>(seq, sg, rg, S, SR);
  dim3 gg(32,4);
  k_gemm_mfma<<<gg,256,0,stream>>>(S,  Wk, Kb);
  k_gemm_mfma<<<gg,256,0,stream>>>(S,  Wv, Vb);
  k_gemm_mfma<<<gg,256,0,stream>>>(SR, Wq, Qb);
  k_small<<<64,256,0,stream>>>(S, SR, Wlr, blr, Wm, bm, Wd, bd, Wgate, LRb, GATEb, MOMb, DECb);
  k_fwd<<<256,256,0,stream>>>(Kb, Vb, LRb, mw1, mw2, mgam, H1B, DH2, GGb);
  k_dw2<<<2048,256,0,stream>>>(H1B, DH2, G2T);
  k_dw1<<<4096,256,0,stream>>>(Kb, DH2, H1B, mw2, G1);
  k_ns_prep<<<512,512,0,stream>>>(G1, G2T);
  for (int it=0; it<5; it++){
    k_nsA<<<512,256,0,stream>>>(G1, G2T, ABh, ABl);
    k_nsB<<<512,256,0,stream>>>(ABh, ABl);
    k_nsZ<<<2048,256,0,stream>>>(G1, G2T, ABh, ABl);
  }
  k_scan_mat<<<512,256,0,stream>>>(G1,  mw1, MOMb, DECb, 0);
  k_scan_mat<<<512,256,0,stream>>>(G2T, mw2, MOMb, DECb, 1);
  k_scan_gamma<<<8,128,0,stream>>>(GGb, mgam, MOMb, DECb);
  k_retr<<<256,256,0,stream>>>(Qb, G1, G2T, GGb, mw1, mw2, mgam, GATEb, OUTT);
  k_gemm_mfma<<<gg,256,0,stream>>>(OUTT, Wc, (float*)d_out);
}

// Round 6
// 1435.334 us; speedup vs baseline: 2.8690x; 1.1178x over previous
//
#include <hip/hip_runtime.h>
#include <hip/hip_bf16.h>
#include <math.h>

#define NN_ 2048

typedef short v8s __attribute__((ext_vector_type(8)));
typedef float v4f __attribute__((ext_vector_type(4)));

__device__ __forceinline__ float geluf(float x){ return 0.5f*x*(1.0f+erff(x*0.70710678118654752440f)); }
__device__ __forceinline__ float gelupf(float x){
  float cdf = 0.5f*(1.0f+erff(x*0.70710678118654752440f));
  float pdf = 0.39894228040143267794f*expf(-0.5f*x*x);
  return cdf + x*pdf;
}
__device__ __forceinline__ float sigm(float x){ return 1.0f/(1.0f+expf(-x)); }

__device__ __forceinline__ unsigned short f2bs(float f){
  __hip_bfloat16 h = __float2bfloat16(f);
  return __builtin_bit_cast(unsigned short, h);
}
__device__ __forceinline__ float bs2f(unsigned short u){
  unsigned v = ((unsigned)u)<<16;
  return __builtin_bit_cast(float, v);
}
__device__ __forceinline__ void hilo(float v, unsigned short &h, unsigned short &l){
  h = f2bs(v); l = f2bs(v - bs2f(h));
}
// XOR-swizzled index into a 128-wide bf16 LDS tile (16B blocks xor'd by row)
__device__ __forceinline__ int swz(int r, int k){
  return r*128 + ((((k>>3) ^ (r&15)) & 15)<<3) + (k&7);
}
// 64-wide variant
__device__ __forceinline__ int swz64(int r, int k){
  return r*64 + ((((k>>3) ^ (r&7)) & 7)<<3) + (k&7);
}

// ---------------- rmsnorm of seq with store/retrieve gains ----------------
__global__ __launch_bounds__(256) void k_rmsnorm(const float* __restrict__ seq, const float* __restrict__ gs,
                          const float* __restrict__ gr, float* __restrict__ S, float* __restrict__ SR){
  int tok = blockIdx.x;
  const float* row = seq + (size_t)tok*512;
  int tid = threadIdx.x;
  float x0 = row[tid];
  float x1 = row[tid+256];
  float ss = x0*x0 + x1*x1;
  #pragma unroll
  for (int o=32;o>0;o>>=1) ss += __shfl_down(ss, o, 64);
  __shared__ float wsum[4];
  int wid = tid>>6, lid = tid&63;
  if (lid==0) wsum[wid]=ss;
  __syncthreads();
  float tot = wsum[0]+wsum[1]+wsum[2]+wsum[3];
  float r = rsqrtf(tot*(1.0f/512.0f) + 1e-6f);
  size_t o0 = (size_t)tok*512 + tid;
  S[o0]      = x0*r*gs[tid];
  S[o0+256]  = x1*r*gs[tid+256];
  SR[o0]     = x0*r*gr[tid];
  SR[o0+256] = x1*r*gr[tid+256];
}

// ---------------- MFMA GEMM: O[4096x512] = X[4096x512] @ Wt[512x512], hi/lo, 64x128 tiles ----------------
__global__ __launch_bounds__(256) void k_gemm_mfma(const float* __restrict__ X, const float* __restrict__ Wt,
                                                   float* __restrict__ O){
  int m0 = blockIdx.x*64, n0 = blockIdx.y*128;
  __shared__ unsigned short Xh[4096], Xl[4096], Wh[8192], Wl[8192];
  int tid = threadIdx.x, w = tid>>6, lane = tid&63, n_l = lane&15, quad = lane>>4;
  v4f acc[8];
  #pragma unroll
  for (int j=0;j<8;j++){ v4f z={0.f,0.f,0.f,0.f}; acc[j]=z; }
  for (int kc=0; kc<8; kc++){
    int k0 = kc*64;
    __syncthreads();
    // stage X tile [64 m][64 k] hi/lo
    for (int it=0; it<4; it++){
      int idx = it*1024 + tid*4;
      int r = idx>>6, k = idx&63;
      float4 v = *(const float4*)(X + (size_t)(m0+r)*512 + k0 + k);
      union { unsigned long long q; unsigned short s[4]; } uh, ul;
      hilo(v.x,uh.s[0],ul.s[0]); hilo(v.y,uh.s[1],ul.s[1]);
      hilo(v.z,uh.s[2],ul.s[2]); hilo(v.w,uh.s[3],ul.s[3]);
      int p = swz64(r,k);
      *(unsigned long long*)&Xh[p] = uh.q;
      *(unsigned long long*)&Xl[p] = ul.q;
    }
    // stage W tile transposed: [128 n][64 k] from Wt[k][n]
    for (int it=0; it<8; it++){
      int idx = it*1024 + tid*4;
      int k = idx>>7, n = idx&127;
      float4 v = *(const float4*)(Wt + (size_t)(k0+k)*512 + n0 + n);
      unsigned short hh,ll;
      hilo(v.x,hh,ll); Wh[swz64(n+0,k)]=hh; Wl[swz64(n+0,k)]=ll;
      hilo(v.y,hh,ll); Wh[swz64(n+1,k)]=hh; Wl[swz64(n+1,k)]=ll;
      hilo(v.z,hh,ll); Wh[swz64(n+2,k)]=hh; Wl[swz64(n+2,k)]=ll;
      hilo(v.w,hh,ll); Wh[swz64(n+3,k)]=hh; Wl[swz64(n+3,k)]=ll;
    }
    __syncthreads();
    #pragma unroll
    for (int ks=0; ks<2; ks++){
      int kf = ks*32 + quad*8;
      v8s ah = *(const v8s*)&Xh[swz64(16*w + n_l, kf)];
      v8s al = *(const v8s*)&Xl[swz64(16*w + n_l, kf)];
      #pragma unroll
      for (int nt=0; nt<8; nt++){
        v8s bh = *(const v8s*)&Wh[swz64(nt*16+n_l, kf)];
        v8s bl = *(const v8s*)&Wl[swz64(nt*16+n_l, kf)];
        acc[nt] = __builtin_amdgcn_mfma_f32_16x16x32_bf16(ah, bh, acc[nt], 0,0,0);
        acc[nt] = __builtin_amdgcn_mfma_f32_16x16x32_bf16(ah, bl, acc[nt], 0,0,0);
        acc[nt] = __builtin_amdgcn_mfma_f32_16x16x32_bf16(al, bh, acc[nt], 0,0,0);
      }
    }
  }
  #pragma unroll
  for (int nt=0; nt<8; nt++)
    #pragma unroll
    for (int r=0;r<4;r++)
      O[(size_t)(m0 + 16*w + quad*4 + r)*512 + n0 + nt*16 + n_l] = acc[nt][r];
}

// ---------------- lr/gate per token, pooled->mom/dec per chunk ----------------
__global__ __launch_bounds__(256) void k_small(const float* __restrict__ S, const float* __restrict__ SR,
    const float* __restrict__ Wlr, const float* __restrict__ blr, const float* __restrict__ Wm,
    const float* __restrict__ bm, const float* __restrict__ Wd, const float* __restrict__ bd,
    const float* __restrict__ Wgate,
    float* __restrict__ LRb, float* __restrict__ GATEb, float* __restrict__ MOMb, float* __restrict__ DECb){
  int bc = blockIdx.x;            // b*32 + ci
  int b = bc>>5, ci = bc&31;
  int tid = threadIdx.x;
  int t = tid>>2, h = tid&3;
  size_t tokbase = (size_t)b*NN_ + (size_t)ci*64;
  __shared__ float pool[512];
  for (int c=tid; c<512; c+=256){
    float s=0;
    for (int t2=0;t2<64;t2++) s += S[(tokbase+t2)*512 + c];
    pool[c] = s*(1.0f/64.0f);
  }
  size_t tok = tokbase + t;
  const float* srow = S + tok*512;
  const float* srrow = SR + tok*512;
  float accl=0, accg=0;
  for (int d=0; d<512; d++){
    accl += srow[d]*Wlr[d*4+h];
    accg += srrow[d]*Wgate[d*4+h];
  }
  accl += blr[h];
  LRb[tok*4+h] = sigm(accl);
  GATEb[tok*4+h] = sigm(accg);
  __syncthreads();
  if (tid<8){
    int hh = tid&3, which = tid>>2;
    float a=0;
    const float* Wx = which? Wd : Wm;
    for (int d=0; d<512; d++) a += pool[d]*Wx[d*4+hh];
    a += which? bd[hh] : bm[hh];
    float v = sigm(a);
    size_t o = ((size_t)b*4+hh)*32 + ci;
    if (which) DECb[o]=v; else MOMb[o]=v;
  }
}

// ---------------- fused memory-MLP forward + rmsnorm backward (MFMA); h1 stored transposed ----------------
__global__ __launch_bounds__(256) void k_fwd(const float* __restrict__ Kb, const float* __restrict__ Vb,
    const float* __restrict__ LRb, const float* __restrict__ mw1, const float* __restrict__ mw2,
    const float* __restrict__ mgamma, float* __restrict__ H1T, float* __restrict__ DH2,
    float* __restrict__ GG){
  int inst = blockIdx.x;
  int ci = inst & 31, h = (inst>>5)&3, b = inst>>7;
  size_t tok0 = (size_t)b*NN_ + (size_t)ci*64;
  int tid = threadIdx.x, w = tid>>6, lane = tid&63, n_l = lane&15, quad = lane>>4;
  __shared__ unsigned short xh[8192];              // [64 t][128 d] swz, hi only
  __shared__ unsigned short wbh[8192], wbl[8192];  // weight tile
  __shared__ unsigned short ash[4096], asl[4096];  // gelu(h1) tile [64 t][64 j] swz64
  const float* w1 = mw1 + (size_t)h*65536;  // [128 d][512 j]
  const float* w2 = mw2 + (size_t)h*65536;  // [512 j][128 d]
  for (int it=0; it<8; it++){
    int idx = it*1024 + tid*4;
    int r = idx>>7, d = idx&127;
    float4 v = *(const float4*)(Kb + (tok0+r)*512 + h*128 + d);
    int p = swz(r,d);
    *(unsigned*)&xh[p]   = (unsigned)f2bs(v.x)|((unsigned)f2bs(v.y)<<16);
    *(unsigned*)&xh[p+2] = (unsigned)f2bs(v.z)|((unsigned)f2bs(v.w)<<16);
  }
  v4f acc2[8];
  #pragma unroll
  for (int j=0;j<8;j++){ v4f z={0.f,0.f,0.f,0.f}; acc2[j]=z; }
  for (int jt=0; jt<8; jt++){
    int j0 = jt*64;
    __syncthreads();
    for (int it=0; it<8; it++){
      int idx = it*1024 + tid*4;
      int d = idx>>6, jj = idx&63;
      float4 v = *(const float4*)(w1 + (size_t)d*512 + j0 + jj);
      unsigned short hh,ll;
      hilo(v.x,hh,ll); wbh[swz(jj+0,d)]=hh; wbl[swz(jj+0,d)]=ll;
      hilo(v.y,hh,ll); wbh[swz(jj+1,d)]=hh; wbl[swz(jj+1,d)]=ll;
      hilo(v.z,hh,ll); wbh[swz(jj+2,d)]=hh; wbl[swz(jj+2,d)]=ll;
      hilo(v.w,hh,ll); wbh[swz(jj+3,d)]=hh; wbl[swz(jj+3,d)]=ll;
    }
    __syncthreads();
    v4f acc1[4];
    #pragma unroll
    for (int nt=0; nt<4; nt++){ v4f z={0.f,0.f,0.f,0.f}; acc1[nt]=z; }
    #pragma unroll
    for (int ks=0; ks<4; ks++){
      int kf = ks*32 + quad*8;
      v8s av = *(const v8s*)&xh[swz(16*w + n_l, kf)];
      #pragma unroll
      for (int nt=0; nt<4; nt++){
        v8s bh = *(const v8s*)&wbh[swz(nt*16+n_l, kf)];
        v8s bl = *(const v8s*)&wbl[swz(nt*16+n_l, kf)];
        acc1[nt] = __builtin_amdgcn_mfma_f32_16x16x32_bf16(av, bh, acc1[nt], 0,0,0);
        acc1[nt] = __builtin_amdgcn_mfma_f32_16x16x32_bf16(av, bl, acc1[nt], 0,0,0);
      }
    }
    // epilogue: H1T (transposed, float4 over t) + gelu -> aS
    #pragma unroll
    for (int nt=0; nt<4; nt++){
      int jj = nt*16 + n_l;
      float4 hv4;
      hv4.x = acc1[nt][0]; hv4.y = acc1[nt][1]; hv4.z = acc1[nt][2]; hv4.w = acc1[nt][3];
      *(float4*)(H1T + (size_t)inst*32768 + (size_t)(j0+jj)*64 + 16*w + quad*4) = hv4;
      #pragma unroll
      for (int r=0;r<4;r++){
        int t = 16*w + quad*4 + r;
        float g = geluf(acc1[nt][r]);
        unsigned short gh = f2bs(g);
        ash[swz64(t, jj)] = gh;
        asl[swz64(t, jj)] = f2bs(g - bs2f(gh));
      }
    }
    __syncthreads();
    for (int it=0; it<8; it++){
      int idx = it*1024 + tid*4;
      int jj = idx>>7, d = idx&127;
      float4 v = *(const float4*)(w2 + (size_t)(j0+jj)*128 + d);
      unsigned short hh,ll;
      hilo(v.x,hh,ll); wbh[swz64(d+0,jj)]=hh; wbl[swz64(d+0,jj)]=ll;
      hilo(v.y,hh,ll); wbh[swz64(d+1,jj)]=hh; wbl[swz64(d+1,jj)]=ll;
      hilo(v.z,hh,ll); wbh[swz64(d+2,jj)]=hh; wbl[swz64(d+2,jj)]=ll;
      hilo(v.w,hh,ll); wbh[swz64(d+3,jj)]=hh; wbl[swz64(d+3,jj)]=ll;
    }
    __syncthreads();
    #pragma unroll
    for (int ks=0; ks<2; ks++){
      int kf = ks*32 + quad*8;
      v8s ah = *(const v8s*)&ash[swz64(16*w + n_l, kf)];
      v8s al = *(const v8s*)&asl[swz64(16*w + n_l, kf)];
      #pragma unroll
      for (int nt=0; nt<8; nt++){
        v8s bh = *(const v8s*)&wbh[swz64(nt*16+n_l, kf)];
        v8s bl = *(const v8s*)&wbl[swz64(nt*16+n_l, kf)];
        acc2[nt] = __builtin_amdgcn_mfma_f32_16x16x32_bf16(ah, bh, acc2[nt], 0,0,0);
        acc2[nt] = __builtin_amdgcn_mfma_f32_16x16x32_bf16(ah, bl, acc2[nt], 0,0,0);
        acc2[nt] = __builtin_amdgcn_mfma_f32_16x16x32_bf16(al, bh, acc2[nt], 0,0,0);
      }
    }
  }
  // phase3: rmsnorm backward on h2 (C-layout)
  float* sgg = (float*)wbh;
  __syncthreads();
  if (tid<128) sgg[tid]=0.0f;
  __syncthreads();
  float ss[4] = {0,0,0,0};
  #pragma unroll
  for (int nt=0; nt<8; nt++)
    #pragma unroll
    for (int r=0;r<4;r++) ss[r] += acc2[nt][r]*acc2[nt][r];
  #pragma unroll
  for (int m=1;m<16;m<<=1)
    #pragma unroll
    for (int r=0;r<4;r++) ss[r] += __shfl_xor(ss[r], m, 64);
  float rr[4];
  #pragma unroll
  for (int r=0;r<4;r++) rr[r] = rsqrtf(ss[r]*(1.0f/128.0f) + 1e-6f);
  float gv[8];
  #pragma unroll
  for (int nt=0; nt<8; nt++) gv[nt] = mgamma[h*128 + nt*16 + n_l];
  float lrv[4];
  #pragma unroll
  for (int r=0;r<4;r++) lrv[r] = LRb[(tok0 + 16*w + quad*4 + r)*4 + h]*(2.0f/128.0f);
  float dnv[8][4]; float dot[4]={0,0,0,0}; float ggp[8];
  #pragma unroll
  for (int nt=0; nt<8; nt++) ggp[nt]=0.0f;
  #pragma unroll
  for (int nt=0; nt<8; nt++)
    #pragma unroll
    for (int r=0;r<4;r++){
      int t = 16*w + quad*4 + r;
      int d = nt*16 + n_l;
      float xv = Kb[(tok0+t)*512 + h*128 + d];
      float vv = Vb[(tok0+t)*512 + h*128 + d];
      float nval = acc2[nt][r]*rr[r];
      float pred = nval*gv[nt] + xv;
      float dp = lrv[r]*(pred - vv);
      ggp[nt] += dp*nval;
      float dn = dp*gv[nt];
      dnv[nt][r] = dn;
      dot[r] += dn*acc2[nt][r];
    }
  #pragma unroll
  for (int nt=0; nt<8; nt++) atomicAdd(&sgg[nt*16+n_l], ggp[nt]);
  #pragma unroll
  for (int m=1;m<16;m<<=1)
    #pragma unroll
    for (int r=0;r<4;r++) dot[r] += __shfl_xor(dot[r], m, 64);
  #pragma unroll
  for (int nt=0; nt<8; nt++)
    #pragma unroll
    for (int r=0;r<4;r++){
      int t = 16*w + quad*4 + r;
      int d = nt*16 + n_l;
      float dt = dot[r]*rr[r]*rr[r]*rr[r]*(1.0f/128.0f);
      DH2[(size_t)inst*8192 + (size_t)t*128 + d] = rr[r]*dnv[nt][r] - dt*acc2[nt][r];
    }
  __syncthreads();
  if (tid<128) GG[(size_t)inst*128+tid] = -sgg[tid];
}

// ---------------- dw2 (MFMA): G2T[d][j] = -sum_t dh2[t,d]*gelu(h1[t,j]) ----------------
__global__ __launch_bounds__(256) void k_dw2(const float* __restrict__ DH2, const float* __restrict__ H1T,
                                             float* __restrict__ G2T){
  int inst = blockIdx.x;
  int tid = threadIdx.x, w = tid>>6, lane = tid&63, n_l = lane&15, quad = lane>>4;
  __shared__ unsigned short d2h[8192], d2l[8192];  // dh2^T [128 d][64 t] swz64 hi/lo
  __shared__ unsigned short ath[8192], atl[8192];  // gelu(h1)^T tile [128 j][64 t] swz64 hi/lo
  for (int it=0; it<8; it++){
    int idx = it*1024 + tid*4;
    int t = idx>>7, d = idx&127;
    float4 v = *(const float4*)(DH2 + (size_t)inst*8192 + idx);
    unsigned short hh,ll;
    hilo(v.x,hh,ll); d2h[swz64(d+0,t)]=hh; d2l[swz64(d+0,t)]=ll;
    hilo(v.y,hh,ll); d2h[swz64(d+1,t)]=hh; d2l[swz64(d+1,t)]=ll;
    hilo(v.z,hh,ll); d2h[swz64(d+2,t)]=hh; d2l[swz64(d+2,t)]=ll;
    hilo(v.w,hh,ll); d2h[swz64(d+3,t)]=hh; d2l[swz64(d+3,t)]=ll;
  }
  for (int jt=0; jt<4; jt++){
    int j0 = jt*128;
    if (jt) __syncthreads();
    for (int it=0; it<8; it++){
      int idx = it*1024 + tid*4;
      int j = idx>>6, t = idx&63;
      float4 v = *(const float4*)(H1T + (size_t)inst*32768 + (size_t)(j0+j)*64 + t);
      union { unsigned long long q; unsigned short s[4]; } uh, ul;
      float g0=geluf(v.x), g1=geluf(v.y), g2=geluf(v.z), g3=geluf(v.w);
      hilo(g0,uh.s[0],ul.s[0]); hilo(g1,uh.s[1],ul.s[1]);
      hilo(g2,uh.s[2],ul.s[2]); hilo(g3,uh.s[3],ul.s[3]);
      int p = swz64(j,t);
      *(unsigned long long*)&ath[p] = uh.q;
      *(unsigned long long*)&atl[p] = ul.q;
    }
    __syncthreads();
    v4f acc[2][8];
    #pragma unroll
    for (int i=0;i<2;i++)
      #pragma unroll
      for (int j=0;j<8;j++){ v4f z={0.f,0.f,0.f,0.f}; acc[i][j]=z; }
    #pragma unroll
    for (int ks=0; ks<2; ks++){
      int kf = ks*32 + quad*8;
      v8s ah[2], al[2];
      #pragma unroll
      for (int i=0;i<2;i++){ int r = 32*w + i*16 + n_l; ah[i]=*(const v8s*)&d2h[swz64(r,kf)]; al[i]=*(const v8s*)&d2l[swz64(r,kf)]; }
      #pragma unroll
      for (int nt=0; nt<8; nt++){
        v8s bh = *(const v8s*)&ath[swz64(nt*16+n_l, kf)];
        v8s bl = *(const v8s*)&atl[swz64(nt*16+n_l, kf)];
        #pragma unroll
        for (int i=0;i<2;i++){
          acc[i][nt] = __builtin_amdgcn_mfma_f32_16x16x32_bf16(ah[i], bh, acc[i][nt], 0,0,0);
          acc[i][nt] = __builtin_amdgcn_mfma_f32_16x16x32_bf16(ah[i], bl, acc[i][nt], 0,0,0);
          acc[i][nt] = __builtin_amdgcn_mfma_f32_16x16x32_bf16(al[i], bh, acc[i][nt], 0,0,0);
        }
      }
    }
    #pragma unroll
    for (int i=0;i<2;i++)
      #pragma unroll
      for (int nt=0; nt<8; nt++)
        #pragma unroll
        for (int r=0;r<4;r++)
          G2T[(size_t)inst*65536 + (size_t)(32*w + i*16 + quad*4 + r)*512 + j0 + nt*16 + n_l] = -acc[i][nt][r];
  }
}

// ---------------- dw1 (MFMA, fused): da^T = w2@dh2^T; dh1 = da*gelu'; G1 = -x^T@dh1 ----------------
__global__ __launch_bounds__(256) void k_dw1(const float* __restrict__ Kb, const float* __restrict__ DH2,
    const float* __restrict__ H1T, const float* __restrict__ mw2, float* __restrict__ G1){
  int inst = blockIdx.x;
  int ci = inst&31, h=(inst>>5)&3, b=inst>>7;
  size_t tok0 = (size_t)b*NN_ + (size_t)ci*64;
  int tid = threadIdx.x, w = tid>>6, lane = tid&63, n_l = lane&15, quad = lane>>4;
  __shared__ unsigned short dh2h[8192];   // dh2 [64 t][128 d] swz, hi
  __shared__ unsigned short xth[8192];    // x^T [128 d][64 t] swz64, hi
  __shared__ unsigned short wb[16384];    // w2 tile [64 j][128 d] swz hi/lo; reused for dh1T hi/lo
  unsigned short* wbl = wb + 8192;
  unsigned short* d1h = wb;               // dh1T [64 j][64 t] swz64 hi
  unsigned short* d1l = wb + 4096;        // dh1T lo
  const float* w2 = mw2 + (size_t)h*65536;
  // stage dh2 hi (native [t][d])
  for (int it=0; it<8; it++){
    int idx = it*1024 + tid*4;
    int t = idx>>7, d = idx&127;
    float4 v = *(const float4*)(DH2 + (size_t)inst*8192 + idx);
    union { unsigned long long q; unsigned short s[4]; } uh;
    uh.s[0]=f2bs(v.x); uh.s[1]=f2bs(v.y); uh.s[2]=f2bs(v.z); uh.s[3]=f2bs(v.w);
    *(unsigned long long*)&dh2h[swz(t,d)] = uh.q;
  }
  // stage x^T hi
  for (int it=0; it<8; it++){
    int idx = it*1024 + tid*4;
    int t = idx>>7, d = idx&127;
    float4 v = *(const float4*)(Kb + (tok0+t)*512 + h*128 + d);
    xth[swz64(d+0,t)] = f2bs(v.x);
    xth[swz64(d+1,t)] = f2bs(v.y);
    xth[swz64(d+2,t)] = f2bs(v.z);
    xth[swz64(d+3,t)] = f2bs(v.w);
  }
  for (int jt=0; jt<8; jt++){
    int j0 = jt*64;
    __syncthreads();
    // stage w2 tile [64 j][128 d] hi/lo
    for (int it=0; it<8; it++){
      int idx = it*1024 + tid*4;
      int jj = idx>>7, d = idx&127;
      float4 v = *(const float4*)(w2 + (size_t)(j0+jj)*128 + d);
      union { unsigned long long q; unsigned short s[4]; } uh, ul;
      hilo(v.x,uh.s[0],ul.s[0]); hilo(v.y,uh.s[1],ul.s[1]);
      hilo(v.z,uh.s[2],ul.s[2]); hilo(v.w,uh.s[3],ul.s[3]);
      int p = swz(jj,d);
      *(unsigned long long*)&wb[p]  = uh.q;
      *(unsigned long long*)&wbl[p] = ul.q;
    }
    __syncthreads();
    // daT: M=64 j, N=64 t, K=128 d
    v4f da[4];
    #pragma unroll
    for (int nt=0; nt<4; nt++){ v4f z={0.f,0.f,0.f,0.f}; da[nt]=z; }
    #pragma unroll
    for (int ks=0; ks<4; ks++){
      int kf = ks*32 + quad*8;
      v8s a_h = *(const v8s*)&wb[swz(16*w + n_l, kf)];
      v8s a_l = *(const v8s*)&wbl[swz(16*w + n_l, kf)];
      #pragma unroll
      for (int nt=0; nt<4; nt++){
        v8s bv = *(const v8s*)&dh2h[swz(nt*16+n_l, kf)];
        da[nt] = __builtin_amdgcn_mfma_f32_16x16x32_bf16(a_h, bv, da[nt], 0,0,0);
        da[nt] = __builtin_amdgcn_mfma_f32_16x16x32_bf16(a_l, bv, da[nt], 0,0,0);
      }
    }
    __syncthreads();
    // dh1T = daT * gelu'(h1T), hi/lo into d1h/d1l (C layout: row j, col t)
    #pragma unroll
    for (int nt=0; nt<4; nt++)
      #pragma unroll
      for (int r=0;r<4;r++){
        int jl = 16*w + quad*4 + r;
        int t = nt*16 + n_l;
        float hv = H1T[(size_t)inst*32768 + (size_t)(j0+jl)*64 + t];
        float d1 = da[nt][r]*gelupf(hv);
        unsigned short hs = f2bs(d1);
        d1h[swz64(jl,t)] = hs;
        d1l[swz64(jl,t)] = f2bs(d1 - bs2f(hs));
      }
    __syncthreads();
    // G1 tile: M=128 d, N=64 j, K=64 t
    v4f g[2][4];
    #pragma unroll
    for (int i=0;i<2;i++)
      #pragma unroll
      for (int nt=0; nt<4; nt++){ v4f z={0.f,0.f,0.f,0.f}; g[i][nt]=z; }
    #pragma unroll
    for (int ks=0; ks<2; ks++){
      int kf = ks*32 + quad*8;
      v8s a_[2];
      #pragma unroll
      for (int i=0;i<2;i++) a_[i] = *(const v8s*)&xth[swz64(32*w + i*16 + n_l, kf)];
      #pragma unroll
      for (int nt=0; nt<4; nt++){
        v8s bh = *(const v8s*)&d1h[swz64(nt*16+n_l, kf)];
        v8s bl = *(const v8s*)&d1l[swz64(nt*16+n_l, kf)];
        #pragma unroll
        for (int i=0;i<2;i++){
          g[i][nt] = __builtin_amdgcn_mfma_f32_16x16x32_bf16(a_[i], bh, g[i][nt], 0,0,0);
          g[i][nt] = __builtin_amdgcn_mfma_f32_16x16x32_bf16(a_[i], bl, g[i][nt], 0,0,0);
        }
      }
    }
    #pragma unroll
    for (int i=0;i<2;i++)
      #pragma unroll
      for (int nt=0; nt<4; nt++)
        #pragma unroll
        for (int r=0;r<4;r++)
          G1[(size_t)inst*65536 + (size_t)(32*w + i*16 + quad*4 + r)*512 + j0 + nt*16 + n_l] = -g[i][nt][r];
  }
}

// ---------------- NS prep: Frobenius-normalize each 128x512 matrix in place (fp32) ----------------
__global__ __launch_bounds__(512) void k_ns_prep(float* __restrict__ G1, float* __restrict__ G2T){
  int m = blockIdx.x;
  float* t = (m<256)? (G1 + (size_t)m*65536) : (G2T + (size_t)(m-256)*65536);
  int tid=threadIdx.x;
  float ss=0;
  for (int idx=tid; idx<65536; idx+=512){ float v=t[idx]; ss+=v*v; }
  #pragma unroll
  for (int o=32;o>0;o>>=1) ss += __shfl_down(ss, o, 64);
  __shared__ float wsum[8];
  int wid=tid>>6, lid=tid&63;
  if (lid==0) wsum[wid]=ss;
  __syncthreads();
  float tot=0;
  #pragma unroll
  for (int w=0;w<8;w++) tot+=wsum[w];
  float scale = 1.0f/fmaxf(sqrtf(tot), 1e-7f);
  for (int idx=tid; idx<65536; idx+=512) t[idx]*=scale;
}

// ---------------- NS step 1: A = t@t^T, split -> ABh/ABl (bf16 planes) ----------------
__global__ __launch_bounds__(256) void k_nsA(const float* __restrict__ G1, const float* __restrict__ G2T,
                                             unsigned short* __restrict__ ABh, unsigned short* __restrict__ ABl){
  int m = blockIdx.x;
  const float* t = (m<256)? (G1 + (size_t)m*65536) : (G2T + (size_t)(m-256)*65536);
  __shared__ unsigned short th[16384];
  __shared__ unsigned short tl[16384];
  int tid = threadIdx.x;
  int w = tid>>6, lane = tid&63;
  int n = lane&15, quad = lane>>4;
  v4f acc[2][8];
  #pragma unroll
  for (int i=0;i<2;i++)
    #pragma unroll
    for (int j=0;j<8;j++){ v4f z = {0.f,0.f,0.f,0.f}; acc[i][j]=z; }
  for (int c=0;c<4;c++){
    int k0 = c*128;
    for (int it=0; it<16; it++){
      int idx = it*1024 + tid*4;
      int r = idx>>7, k = idx&127;
      float4 v = *(const float4*)(t + (size_t)r*512 + k0 + k);
      union { unsigned long long q; unsigned short s[4]; } uh, ulw;
      uh.s[0]=f2bs(v.x); uh.s[1]=f2bs(v.y); uh.s[2]=f2bs(v.z); uh.s[3]=f2bs(v.w);
      ulw.s[0]=f2bs(v.x-bs2f(uh.s[0])); ulw.s[1]=f2bs(v.y-bs2f(uh.s[1]));
      ulw.s[2]=f2bs(v.z-bs2f(uh.s[2])); ulw.s[3]=f2bs(v.w-bs2f(uh.s[3]));
      *(unsigned long long*)&th[swz(r,k)] = uh.q;
      *(unsigned long long*)&tl[swz(r,k)] = ulw.q;
    }
    __syncthreads();
    for (int kk=0; kk<128; kk+=32){
      int kf = kk + quad*8;
      v8s ah[2], al[2], bh[8], bl[8];
      #pragma unroll
      for (int i=0;i<2;i++){ int r = w*32 + i*16 + n; ah[i]=*(const v8s*)&th[swz(r,kf)]; al[i]=*(const v8s*)&tl[swz(r,kf)]; }
      #pragma unroll
      for (int j=0;j<8;j++){ int r = j*16 + n; bh[j]=*(const v8s*)&th[swz(r,kf)]; bl[j]=*(const v8s*)&tl[swz(r,kf)]; }
      #pragma unroll
      for (int i=0;i<2;i++)
        #pragma unroll
        for (int j=0;j<8;j++){
          acc[i][j] = __builtin_amdgcn_mfma_f32_16x16x32_bf16(ah[i], bh[j], acc[i][j], 0,0,0);
          acc[i][j] = __builtin_amdgcn_mfma_f32_16x16x32_bf16(ah[i], bl[j], acc[i][j], 0,0,0);
          acc[i][j] = __builtin_amdgcn_mfma_f32_16x16x32_bf16(al[i], bh[j], acc[i][j], 0,0,0);
        }
    }
    __syncthreads();
  }
  #pragma unroll
  for (int i=0;i<2;i++)
    #pragma unroll
    for (int j=0;j<8;j++)
      #pragma unroll
      for (int r=0;r<4;r++){
        int row = w*32 + i*16 + quad*4 + r;
        int col = j*16 + n;
        float v = acc[i][j][r];
        unsigned short hs = f2bs(v);
        th[row*128+col] = hs;
        tl[row*128+col] = f2bs(v - bs2f(hs));
      }
  __syncthreads();
  for (int it=0; it<8; it++){
    int idx = it*2048 + tid*8;
    *(v8s*)&ABh[(size_t)m*16384 + idx] = *(const v8s*)&th[idx];
    *(v8s*)&ABl[(size_t)m*16384 + idx] = *(const v8s*)&tl[idx];
  }
}

// ---------------- NS step 2: B = b*A + c*A@A, split, in-place over AB planes ----------------
__global__ __launch_bounds__(256) void k_nsB(unsigned short* __restrict__ ABh, unsigned short* __restrict__ ABl){
  int m = blockIdx.x;
  __shared__ unsigned short Ah[16384];
  __shared__ unsigned short Al[16384];
  int tid = threadIdx.x;
  int w = tid>>6, lane = tid&63;
  int n = lane&15, quad = lane>>4;
  for (int it=0; it<8; it++){
    int idx = it*2048 + tid*8;
    int r = idx>>7, k = idx&127;
    *(v8s*)&Ah[swz(r,k)] = *(const v8s*)&ABh[(size_t)m*16384 + idx];
    *(v8s*)&Al[swz(r,k)] = *(const v8s*)&ABl[(size_t)m*16384 + idx];
  }
  __syncthreads();
  v4f acc[2][8];
  #pragma unroll
  for (int i=0;i<2;i++)
    #pragma unroll
    for (int j=0;j<8;j++){ v4f z = {0.f,0.f,0.f,0.f}; acc[i][j]=z; }
  for (int kk=0; kk<128; kk+=32){
    int kf = kk + quad*8;
    v8s ah[2], al2[2], bh[8], bl[8];
    #pragma unroll
    for (int i=0;i<2;i++){ int r = w*32 + i*16 + n; ah[i]=*(const v8s*)&Ah[swz(r,kf)]; al2[i]=*(const v8s*)&Al[swz(r,kf)]; }
    #pragma unroll
    for (int j=0;j<8;j++){ int r = j*16 + n; bh[j]=*(const v8s*)&Ah[swz(r,kf)]; bl[j]=*(const v8s*)&Al[swz(r,kf)]; }
    #pragma unroll
    for (int i=0;i<2;i++)
      #pragma unroll
      for (int j=0;j<8;j++){
        acc[i][j] = __builtin_amdgcn_mfma_f32_16x16x32_bf16(ah[i], bh[j], acc[i][j], 0,0,0);
        acc[i][j] = __builtin_amdgcn_mfma_f32_16x16x32_bf16(ah[i], bl[j], acc[i][j], 0,0,0);
        acc[i][j] = __builtin_amdgcn_mfma_f32_16x16x32_bf16(al2[i], bh[j], acc[i][j], 0,0,0);
      }
  }
  const float CB=-4.775f, CC=2.0315f;
  float Bv[2][8][4];
  #pragma unroll
  for (int i=0;i<2;i++)
    #pragma unroll
    for (int j=0;j<8;j++)
      #pragma unroll
      for (int r=0;r<4;r++){
        int row = w*32 + i*16 + quad*4 + r;
        int col = j*16 + n;
        float av = bs2f(Ah[swz(row,col)]) + bs2f(Al[swz(row,col)]);
        Bv[i][j][r] = CB*av + CC*acc[i][j][r];
      }
  __syncthreads();
  #pragma unroll
  for (int i=0;i<2;i++)
    #pragma unroll
    for (int j=0;j<8;j++)
      #pragma unroll
      for (int r=0;r<4;r++){
        int row = w*32 + i*16 + quad*4 + r;
        int col = j*16 + n;
        float v = Bv[i][j][r];
        unsigned short hs = f2bs(v);
        Ah[row*128+col] = hs;
        Al[row*128+col] = f2bs(v - bs2f(hs));
      }
  __syncthreads();
  for (int it=0; it<8; it++){
    int idx = it*2048 + tid*8;
    *(v8s*)&ABh[(size_t)m*16384 + idx] = *(const v8s*)&Ah[idx];
    *(v8s*)&ABl[(size_t)m*16384 + idx] = *(const v8s*)&Al[idx];
  }
}

// ---------------- NS step 3: t' = a*t + B@t per 128-col strip (B symmetric), in place ----------------
__global__ __launch_bounds__(256) void k_nsZ(float* __restrict__ G1, float* __restrict__ G2T,
                                             const unsigned short* __restrict__ ABh, const unsigned short* __restrict__ ABl){
  int blk = blockIdx.x;
  int m = blk>>2, s = blk&3, c0 = s*128;
  float* t = (m<256)? (G1 + (size_t)m*65536) : (G2T + (size_t)(m-256)*65536);
  __shared__ __align__(16) unsigned char smem[65536];
  unsigned short* Bh = (unsigned short*)smem;
  unsigned short* Bl = Bh + 8192;
  unsigned short* uh = Bh + 16384;
  unsigned short* ul = Bh + 24576;
  float* Zs = (float*)smem;
  int tid = threadIdx.x;
  int w = tid>>6, lane = tid&63;
  int n = lane&15, quad = lane>>4;
  v4f acc[2][8];
  #pragma unroll
  for (int i=0;i<2;i++)
    #pragma unroll
    for (int j=0;j<8;j++){ v4f z = {0.f,0.f,0.f,0.f}; acc[i][j]=z; }
  for (int c=0;c<2;c++){
    int k0 = c*64;
    for (int it=0; it<4; it++){
      int idx = it*2048 + tid*8;
      int r = idx>>6, k = idx&63;
      *(v8s*)&Bh[swz64(r,k)] = *(const v8s*)&ABh[(size_t)m*16384 + (size_t)r*128 + k0 + k];
      *(v8s*)&Bl[swz64(r,k)] = *(const v8s*)&ABl[(size_t)m*16384 + (size_t)r*128 + k0 + k];
    }
    for (int it=0; it<8; it++){
      int idx = it*1024 + tid*4;
      int kr = idx>>7, j = idx&127;
      float4 v = *(const float4*)(t + (size_t)(k0+kr)*512 + c0 + j);
      float vv[4] = {v.x, v.y, v.z, v.w};
      #pragma unroll
      for (int e=0;e<4;e++){
        unsigned short hs = f2bs(vv[e]);
        uh[swz64(j+e, kr)] = hs;
        ul[swz64(j+e, kr)] = f2bs(vv[e] - bs2f(hs));
      }
    }
    __syncthreads();
    #pragma unroll
    for (int kk=0; kk<64; kk+=32){
      int kf = kk + quad*8;
      v8s ah[2], al2[2], bhf[8], blf[8];
      #pragma unroll
      for (int i=0;i<2;i++){ int r = w*32 + i*16 + n; ah[i]=*(const v8s*)&Bh[swz64(r,kf)]; al2[i]=*(const v8s*)&Bl[swz64(r,kf)]; }
      #pragma unroll
      for (int j=0;j<8;j++){ int r = j*16 + n; bhf[j]=*(const v8s*)&uh[swz64(r,kf)]; blf[j]=*(const v8s*)&ul[swz64(r,kf)]; }
      #pragma unroll
      for (int i=0;i<2;i++)
        #pragma unroll
        for (int j=0;j<8;j++){
          acc[i][j] = __builtin_amdgcn_mfma_f32_16x16x32_bf16(ah[i], bhf[j], acc[i][j], 0,0,0);
          acc[i][j] = __builtin_amdgcn_mfma_f32_16x16x32_bf16(ah[i], blf[j], acc[i][j], 0,0,0);
          acc[i][j] = __builtin_amdgcn_mfma_f32_16x16x32_bf16(al2[i], bhf[j], acc[i][j], 0,0,0);
        }
    }
    __syncthreads();
  }
  #pragma unroll
  for (int i=0;i<2;i++)
    #pragma unroll
    for (int j=0;j<8;j++)
      #pragma unroll
      for (int r=0;r<4;r++){
        int row = w*32 + i*16 + quad*4 + r;
        int col = j*16 + n;
        Zs[row*128+col] = acc[i][j][r];
      }
  __syncthreads();
  const float CA = 3.4445f;
  for (int it=0; it<16; it++){
    int idx = it*1024 + tid*4;
    int i = idx>>7, j = idx&127;
    float* dst = t + (size_t)i*512 + c0 + j;
    float4 told = *(const float4*)dst;
    float4 o;
    o.x = CA*told.x + Zs[i*128+j+0];
    o.y = CA*told.y + Zs[i*128+j+1];
    o.z = CA*told.z + Zs[i*128+j+2];
    o.w = CA*told.w + Zs[i*128+j+3];
    *(float4*)dst = o;
  }
}

// ---------------- momentum + decay scans (float4/thread, prefetch), per (b,h) strand ----------------
__global__ __launch_bounds__(256) void k_scan_mat(float* __restrict__ G, const float* __restrict__ mw,
    const float* __restrict__ MOMb, const float* __restrict__ DECb, int transposed){
  int bh = blockIdx.x>>6;
  int eblk = blockIdx.x&63;
  int e = (eblk*256 + threadIdx.x)*4;
  int h = bh&3;
  float4 u;
  if (transposed){
    int d = e>>9; int j = e&511;
    u.x = mw[(size_t)h*65536 + (size_t)(j+0)*128 + d];
    u.y = mw[(size_t)h*65536 + (size_t)(j+1)*128 + d];
    u.z = mw[(size_t)h*65536 + (size_t)(j+2)*128 + d];
    u.w = mw[(size_t)h*65536 + (size_t)(j+3)*128 + d];
  } else {
    u = *(const float4*)(mw + (size_t)h*65536 + e);
  }
  float4 mval = {0,0,0,0};
  size_t base = (size_t)(bh*32)*65536 + e;
  float4 s = *(const float4*)(G + base);
  for (int ci=0; ci<32; ci++){
    size_t off = base + (size_t)ci*65536;
    float4 s_next;
    if (ci<31) s_next = *(const float4*)(G + off + 65536);
    float mo = MOMb[bh*32+ci], de = DECb[bh*32+ci];
    float om = 1.0f-de;
    mval.x = mo*mval.x + s.x; mval.y = mo*mval.y + s.y;
    mval.z = mo*mval.z + s.z; mval.w = mo*mval.w + s.w;
    u.x = om*u.x + mval.x; u.y = om*u.y + mval.y;
    u.z = om*u.z + mval.z; u.w = om*u.w + mval.w;
    *(float4*)(G + off) = u;
    s = s_next;
  }
}

__global__ __launch_bounds__(128) void k_scan_gamma(float* __restrict__ GG, const float* __restrict__ mg,
    const float* __restrict__ MOMb, const float* __restrict__ DECb){
  int bh=blockIdx.x; int e=threadIdx.x; int h=bh&3;
  float u = mg[h*128+e]; float mval=0;
  for (int ci=0;ci<32;ci++){
    size_t off = ((size_t)(bh*32+ci))*128 + e;
    float s = GG[off];
    float mo = MOMb[bh*32+ci], de = DECb[bh*32+ci];
    mval = mo*mval + s;
    u = (1.0f-de)*u + mval;
    GG[off]=u;
  }
}

// ---------------- retrieval: mem_forward with shifted weights (MFMA), gated ----------------
__global__ __launch_bounds__(256) void k_retr(const float* __restrict__ Qb, const float* __restrict__ G1,
   const float* __restrict__ G2T, const float* __restrict__ GG, const float* __restrict__ mw1,
   const float* __restrict__ mw2, const float* __restrict__ mgamma,
   const float* __restrict__ GATEb, float* __restrict__ OUTT){
  int inst = blockIdx.x;
  int ci = inst & 31, h = (inst>>5)&3, b = inst>>7;
  size_t tok0 = (size_t)b*NN_ + (size_t)ci*64;
  int tid = threadIdx.x, w = tid>>6, lane = tid&63, n_l = lane&15, quad = lane>>4;
  __shared__ unsigned short xh[8192];
  __shared__ unsigned short wbh[8192], wbl[8192];
  __shared__ unsigned short ash[4096], asl[4096];
  const int first = (ci==0);
  const float* w1 = first ? (mw1 + (size_t)h*65536) : (G1 + (size_t)(inst-1)*65536);   // [128 d][512 j]
  const float* w2j = mw2 + (size_t)h*65536;                                            // [512 j][128 d]
  const float* w2d = G2T + (size_t)(inst-1)*65536;                                     // [128 d][512 j]
  for (int it=0; it<8; it++){
    int idx = it*1024 + tid*4;
    int r = idx>>7, d = idx&127;
    float4 v = *(const float4*)(Qb + (tok0+r)*512 + h*128 + d);
    int p = swz(r,d);
    *(unsigned*)&xh[p]   = (unsigned)f2bs(v.x)|((unsigned)f2bs(v.y)<<16);
    *(unsigned*)&xh[p+2] = (unsigned)f2bs(v.z)|((unsigned)f2bs(v.w)<<16);
  }
  v4f acc2[8];
  #pragma unroll
  for (int j=0;j<8;j++){ v4f z={0.f,0.f,0.f,0.f}; acc2[j]=z; }
  for (int jt=0; jt<8; jt++){
    int j0 = jt*64;
    __syncthreads();
    for (int it=0; it<8; it++){
      int idx = it*1024 + tid*4;
      int d = idx>>6, jj = idx&63;
      float4 v = *(const float4*)(w1 + (size_t)d*512 + j0 + jj);
      unsigned short hh,ll;
      hilo(v.x,hh,ll); wbh[swz(jj+0,d)]=hh; wbl[swz(jj+0,d)]=ll;
      hilo(v.y,hh,ll); wbh[swz(jj+1,d)]=hh; wbl[swz(jj+1,d)]=ll;
      hilo(v.z,hh,ll); wbh[swz(jj+2,d)]=hh; wbl[swz(jj+2,d)]=ll;
      hilo(v.w,hh,ll); wbh[swz(jj+3,d)]=hh; wbl[swz(jj+3,d)]=ll;
    }
    __syncthreads();
    v4f acc1[4];
    #pragma unroll
    for (int nt=0; nt<4; nt++){ v4f z={0.f,0.f,0.f,0.f}; acc1[nt]=z; }
    #pragma unroll
    for (int ks=0; ks<4; ks++){
      int kf = ks*32 + quad*8;
      v8s av = *(const v8s*)&xh[swz(16*w + n_l, kf)];
      #pragma unroll
      for (int nt=0; nt<4; nt++){
        v8s bh = *(const v8s*)&wbh[swz(nt*16+n_l, kf)];
        v8s bl = *(const v8s*)&wbl[swz(nt*16+n_l, kf)];
        acc1[nt] = __builtin_amdgcn_mfma_f32_16x16x32_bf16(av, bh, acc1[nt], 0,0,0);
        acc1[nt] = __builtin_amdgcn_mfma_f32_16x16x32_bf16(av, bl, acc1[nt], 0,0,0);
      }
    }
    #pragma unroll
    for (int nt=0; nt<4; nt++)
      #pragma unroll
      for (int r=0;r<4;r++){
        int t = 16*w + quad*4 + r;
        int jj = nt*16 + n_l;
        float g = geluf(acc1[nt][r]);
        unsigned short gh = f2bs(g);
        ash[swz64(t, jj)] = gh;
        asl[swz64(t, jj)] = f2bs(g - bs2f(gh));
      }
    __syncthreads();
    if (first){
      for (int it=0; it<8; it++){
        int idx = it*1024 + tid*4;
        int jj = idx>>7, d = idx&127;
        float4 v = *(const float4*)(w2j + (size_t)(j0+jj)*128 + d);
        unsigned short hh,ll;
        hilo(v.x,hh,ll); wbh[swz64(d+0,jj)]=hh; wbl[swz64(d+0,jj)]=ll;
        hilo(v.y,hh,ll); wbh[swz64(d+1,jj)]=hh; wbl[swz64(d+1,jj)]=ll;
        hilo(v.z,hh,ll); wbh[swz64(d+2,jj)]=hh; wbl[swz64(d+2,jj)]=ll;
        hilo(v.w,hh,ll); wbh[swz64(d+3,jj)]=hh; wbl[swz64(d+3,jj)]=ll;
      }
    } else {
      for (int it=0; it<8; it++){
        int idx = it*1024 + tid*4;
        int d = idx>>6, jj = idx&63;
        float4 v = *(const float4*)(w2d + (size_t)d*512 + j0 + jj);
        unsigned short h0,h1,h2,h3,l0,l1,l2,l3;
        hilo(v.x,h0,l0); hilo(v.y,h1,l1); hilo(v.z,h2,l2); hilo(v.w,h3,l3);
        int p = swz64(d,jj);
        *(unsigned*)&wbh[p]   = (unsigned)h0|((unsigned)h1<<16);
        *(unsigned*)&wbh[p+2] = (unsigned)h2|((unsigned)h3<<16);
        *(unsigned*)&wbl[p]   = (unsigned)l0|((unsigned)l1<<16);
        *(unsigned*)&wbl[p+2] = (unsigned)l2|((unsigned)l3<<16);
      }
    }
    __syncthreads();
    #pragma unroll
    for (int ks=0; ks<2; ks++){
      int kf = ks*32 + quad*8;
      v8s ah = *(const v8s*)&ash[swz64(16*w + n_l, kf)];
      v8s al = *(const v8s*)&asl[swz64(16*w + n_l, kf)];
      #pragma unroll
      for (int nt=0; nt<8; nt++){
        v8s bh = *(const v8s*)&wbh[swz64(nt*16+n_l, kf)];
        v8s bl = *(const v8s*)&wbl[swz64(nt*16+n_l, kf)];
        acc2[nt] = __builtin_amdgcn_mfma_f32_16x16x32_bf16(ah, bh, acc2[nt], 0,0,0);
        acc2[nt] = __builtin_amdgcn_mfma_f32_16x16x32_bf16(ah, bl, acc2[nt], 0,0,0);
        acc2[nt] = __builtin_amdgcn_mfma_f32_16x16x32_bf16(al, bh, acc2[nt], 0,0,0);
      }
    }
  }
  float ss[4] = {0,0,0,0};
  #pragma unroll
  for (int nt=0; nt<8; nt++)
    #pragma unroll
    for (int r=0;r<4;r++) ss[r] += acc2[nt][r]*acc2[nt][r];
  #pragma unroll
  for (int m=1;m<16;m<<=1)
    #pragma unroll
    for (int r=0;r<4;r++) ss[r] += __shfl_xor(ss[r], m, 64);
  float rr[4];
  #pragma unroll
  for (int r=0;r<4;r++) rr[r] = rsqrtf(ss[r]*(1.0f/128.0f) + 1e-6f);
  float gv[8];
  #pragma unroll
  for (int nt=0; nt<8; nt++){
    int d = nt*16 + n_l;
    gv[nt] = first ? mgamma[h*128+d] : GG[(size_t)(inst-1)*128+d];
  }
  float gate[4];
  #pragma unroll
  for (int r=0;r<4;r++) gate[r] = GATEb[(tok0 + 16*w + quad*4 + r)*4 + h];
  #pragma unroll
  for (int nt=0; nt<8; nt++)
    #pragma unroll
    for (int r=0;r<4;r++){
      int t = 16*w + quad*4 + r;
      int d = nt*16 + n_l;
      float qv = Qb[(tok0+t)*512 + h*128 + d];
      OUTT[(tok0+t)*512 + h*128 + d] = (acc2[nt][r]*rr[r]*gv[nt] + qv)*gate[r];
    }
}

extern "C" void kernel_launch(void* const* d_in, const int* in_sizes, int n_in,
                              void* d_out, int out_size, void* d_ws, size_t ws_size,
                              hipStream_t stream) {
  (void)in_sizes; (void)n_in; (void)out_size; (void)ws_size;
  const float* seq   = (const float*)d_in[0];
  const float* sg    = (const float*)d_in[1];
  const float* rg    = (const float*)d_in[2];
  const float* Wq    = (const float*)d_in[3];
  const float* Wk    = (const float*)d_in[4];
  const float* Wv    = (const float*)d_in[5];
  const float* Wlr   = (const float*)d_in[6];
  const float* blr   = (const float*)d_in[7];
  const float* Wm    = (const float*)d_in[8];
  const float* bm    = (const float*)d_in[9];
  const float* Wd    = (const float*)d_in[10];
  const float* bd    = (const float*)d_in[11];
  const float* Wgate = (const float*)d_in[12];
  const float* Wc    = (const float*)d_in[13];
  const float* mw1   = (const float*)d_in[14];
  const float* mw2   = (const float*)d_in[15];
  const float* mgam  = (const float*)d_in[16];

  float* W = (float*)d_ws;
  float* S    = W + 0;
  float* SR   = W + 2097152;
  float* Kb   = W + 4194304;
  float* Vb   = W + 6291456;
  float* H1T  = W + 8388608;
  float* DH2  = W + 16777216;
  float* Qb   = W + 18874368;
  float* LRb  = W + 20971520;
  float* GATEb= W + 20987904;
  float* MOMb = W + 21004288;
  float* DECb = W + 21004544;
  float* GGb  = W + 21004800;
  float* G1   = W + 21037568;
  float* G2T  = W + 37814784;
  unsigned short* ABh = (unsigned short*)(W + 0);        // overlay S+SR (dead by NS time)
  unsigned short* ABl = (unsigned short*)(W + 4194304);  // overlay Kb+Vb (dead after k_dw1)
  float* OUTT = W + 8388608;  // overlay H1T slot (free by retrieval time)

  k_rmsnorm<<<4096,256,0,stream>>>(seq, sg, rg, S, SR);
  dim3 gg(64,4);
  k_gemm_mfma<<<gg,256,0,stream>>>(S,  Wk, Kb);
  k_gemm_mfma<<<gg,256,0,stream>>>(S,  Wv, Vb);
  k_gemm_mfma<<<gg,256,0,stream>>>(SR, Wq, Qb);
  k_small<<<64,256,0,stream>>>(S, SR, Wlr, blr, Wm, bm, Wd, bd, Wgate, LRb, GATEb, MOMb, DECb);
  k_fwd<<<256,256,0,stream>>>(Kb, Vb, LRb, mw1, mw2, mgam, H1T, DH2, GGb);
  k_dw2<<<256,256,0,stream>>>(DH2, H1T, G2T);
  k_dw1<<<256,256,0,stream>>>(Kb, DH2, H1T, mw2, G1);
  k_ns_prep<<<512,512,0,stream>>>(G1, G2T);
  for (int it=0; it<5; it++){
    k_nsA<<<512,256,0,stream>>>(G1, G2T, ABh, ABl);
    k_nsB<<<512,256,0,stream>>>(ABh, ABl);
    k_nsZ<<<2048,256,0,stream>>>(G1, G2T, ABh, ABl);
  }
  k_scan_mat<<<512,256,0,stream>>>(G1,  mw1, MOMb, DECb, 0);
  k_scan_mat<<<512,256,0,stream>>>(G2T, mw2, MOMb, DECb, 1);
  k_scan_gamma<<<8,128,0,stream>>>(GGb, mgam, MOMb, DECb);
  k_retr<<<256,256,0,stream>>>(Qb, G1, G2T, GGb, mw1, mw2, mgam, GATEb, OUTT);
  k_gemm_mfma<<<gg,256,0,stream>>>(OUTT, Wc, (float*)d_out);
}